// Round 1
// baseline (446.733 us; speedup 1.0000x reference)
//
#include <hip/hip_runtime.h>

// ---------------------------------------------------------------------------
// STD-DAGMM loss, B=262144, K=8, D=32, fp32.
// ws layout (floats):
//   [0      .. 8191 ] S2[k][d][e] raw second moment  Σ γ f fᵀ
//   [8192   .. 8447 ] S1[k][d]                       Σ γ f
//   [8448   .. 8455 ] gsum[k]                        Σ γ
//   [8456]            singularity_loss
//   [8457]            energy sum
//   [8458]            recon sum
//   [8464   .. 8471 ] c1[k] = log(phi+1e-10) - 0.5*(logdet + D*log(2*3.14159))
//   [8472   .. 8727 ] lmu[k][j] = (Linv_k · mu_k)[j]
//   [8736   .. 16927] Linv[k][j][i] (full 32x32, upper zeros)
// ---------------------------------------------------------------------------

#define B_SIZE 262144
#define NBLK_MOM 512

// Kernel 1: fused raw moments (gsum, S1, S2) in one pass.
// Each lane owns a strided 4x4 (d,e) tile for ALL 8 k (128 acc regs).
__global__ __launch_bounds__(256, 2) void k_moments(
    const float* __restrict__ gamma, const float* __restrict__ feat,
    float* __restrict__ ws) {
  __shared__ float s2l[8 * 32 * 40];  // stride-40 rows: ds_add bank = (8*d_blk+e_blk)%32 -> 2-way (free)
  __shared__ float s1l[8 * 40];
  __shared__ float gsl[8];
  const int tid = threadIdx.x;
  for (int t = tid; t < 8 * 32 * 40; t += 256) s2l[t] = 0.f;
  for (int t = tid; t < 8 * 40; t += 256) s1l[t] = 0.f;
  if (tid < 8) gsl[tid] = 0.f;
  __syncthreads();

  const int lane = tid & 63;
  const int wave = tid >> 6;
  const int gw = blockIdx.x * 4 + wave;          // 0..2047
  const int d_blk = (lane >> 3) & 7;
  const int e_blk = lane & 7;
  const int ROWS = B_SIZE / (NBLK_MOM * 4);      // 128
  const int b0 = gw * ROWS;

  float acc[8][16];
#pragma unroll
  for (int k = 0; k < 8; ++k)
#pragma unroll
    for (int t = 0; t < 16; ++t) acc[k][t] = 0.f;
  float s1a[4] = {0.f, 0.f, 0.f, 0.f};
  float gacc = 0.f;

  const float* fr = feat + (size_t)b0 * 32;
  const float* gr = gamma + (size_t)b0 * 8;
  for (int r = 0; r < ROWS; ++r) {
    float fdv[4], fev[4];
#pragma unroll
    for (int q = 0; q < 4; ++q) {
      fdv[q] = fr[d_blk + 8 * q];
      fev[q] = fr[e_blk + 8 * q];
    }
    const float4 g0 = *(const float4*)(gr);
    const float4 g1 = *(const float4*)(gr + 4);
    const float ge = gr[e_blk];
    const float g[8] = {g0.x, g0.y, g0.z, g0.w, g1.x, g1.y, g1.z, g1.w};
#pragma unroll
    for (int k = 0; k < 8; ++k) {
      const float t0 = g[k] * fdv[0], t1 = g[k] * fdv[1];
      const float t2 = g[k] * fdv[2], t3 = g[k] * fdv[3];
#pragma unroll
      for (int j = 0; j < 4; ++j) {
        acc[k][0 + j]  += t0 * fev[j];
        acc[k][4 + j]  += t1 * fev[j];
        acc[k][8 + j]  += t2 * fev[j];
        acc[k][12 + j] += t3 * fev[j];
      }
    }
#pragma unroll
    for (int q = 0; q < 4; ++q) s1a[q] += ge * fdv[q];
    gacc += ge;
    fr += 32;
    gr += 8;
  }

  // block-level LDS accumulation (2-way banks by construction)
#pragma unroll
  for (int k = 0; k < 8; ++k)
#pragma unroll
    for (int i2 = 0; i2 < 4; ++i2)
#pragma unroll
      for (int j2 = 0; j2 < 4; ++j2)
        atomicAdd(&s2l[k * 1280 + (d_blk + 8 * i2) * 40 + (e_blk + 8 * j2)],
                  acc[k][i2 * 4 + j2]);
#pragma unroll
  for (int q = 0; q < 4; ++q)
    atomicAdd(&s1l[e_blk * 40 + d_blk + 8 * q], s1a[q]);
  if (d_blk == 0) atomicAdd(&gsl[e_blk], gacc);
  __syncthreads();

  // one set of global atomics per block
  for (int t = tid; t < 8192; t += 256) {
    const int k = t >> 10, rem = t & 1023, d = rem >> 5, e = rem & 31;
    atomicAdd(&ws[t], s2l[k * 1280 + d * 40 + e]);
  }
  if (tid < 256) {
    const int k = tid >> 5, d = tid & 31;
    atomicAdd(&ws[8192 + tid], s1l[k * 40 + d]);
  }
  if (tid < 8) atomicAdd(&ws[8448 + tid], gsl[tid]);
}

// Kernel 2: sigma assembly, Cholesky, Linv, logdet, c1, lmu, singularity.
// One block, 256 threads = 8 k-groups x 32 lanes.
__global__ void k_prepare(float* __restrict__ ws) {
  __shared__ float A[8][32][33];
  __shared__ float Lv[8][32][33];
  __shared__ float mu_s[8][32];
  __shared__ float red[256];
  const int tid = threadIdx.x;
  const int k = tid >> 5;
  const int i = tid & 31;

  const float gs = ws[8448 + k];
  const float denom = gs + 1e-8f;
  const float s1i = ws[8192 + k * 32 + i];
  const float mu_i = s1i / denom;
  mu_s[k][i] = mu_i;
  __syncthreads();

  // sigma row i for group k:  (S2 - mu S1^T - S1 mu^T + gs mu mu^T)/denom + eps I
  float sing = 0.f;
  for (int j = 0; j < 32; ++j) {
    const float s2 = ws[k * 1024 + i * 32 + j];
    const float muj = mu_s[k][j];
    const float s1j = ws[8192 + k * 32 + j];
    const float num = s2 - mu_i * s1j - muj * s1i + gs * mu_i * muj;
    const float sig = num / denom + ((i == j) ? 1e-6f : 0.f);
    A[k][i][j] = sig;
    if (i == j) sing = 1.f / (sig + 1e-8f);
  }
  red[tid] = sing;
  __syncthreads();
  if (tid == 0) {
    float s = 0.f;
    for (int t = 0; t < 256; ++t) s += red[t];
    ws[8456] = s;
  }
  __syncthreads();

  // right-looking Cholesky, in place in A (lower triangle)
  for (int j = 0; j < 32; ++j) {
    const float ljj = sqrtf(A[k][j][j]);
    float lij;
    if (i == j)      lij = ljj;
    else if (i > j)  lij = A[k][i][j] / ljj;
    else             lij = 0.f;
    A[k][i][j] = lij;
    __syncthreads();
    for (int p = j + 1; p < 32; ++p) {
      const float lpj = A[k][p][j];
      if (p <= i) A[k][i][p] -= lij * lpj;
    }
    __syncthreads();
  }

  // forward substitution: lane i solves L x = e_i  -> column i of Linv
  float x[32];
#pragma unroll
  for (int r = 0; r < 32; ++r) {
    float s = (r == i) ? 1.f : 0.f;
#pragma unroll
    for (int p = 0; p < r; ++p) s -= A[k][r][p] * x[p];
    x[r] = s / A[k][r][r];
  }
#pragma unroll
  for (int r = 0; r < 32; ++r) {
    Lv[k][r][i] = x[r];
    ws[8736 + k * 1024 + r * 32 + i] = x[r];
  }
  __syncthreads();

  // lmu[j] = (Linv mu)[j]
  float lm = 0.f;
  for (int p = 0; p < 32; ++p) lm += Lv[k][i][p] * mu_s[k][p];
  ws[8472 + k * 32 + i] = lm;

  // logdet + c1
  red[tid] = logf(A[k][i][i]);
  __syncthreads();
  if (i == 0) {
    float ld = 0.f;
    for (int t = 0; t < 32; ++t) ld += red[k * 32 + t];
    ld *= 2.f;
    const float phi = gs * (1.f / (float)B_SIZE);
    ws[8464 + k] = logf(phi + 1e-10f) - 0.5f * (ld + 32.f * logf(6.28318f));
  }
}

// Kernel 3: per-sample mahalanobis via ||Linv (f - mu)||^2, online logsumexp,
// energy + recon reduction.
__global__ __launch_bounds__(256) void k_energy(
    const float* __restrict__ feat, const float* __restrict__ rec,
    const float* __restrict__ cws, float* __restrict__ aws) {
  const int b = blockIdx.x * 256 + threadIdx.x;
  float f[32];
  const float4* fp = (const float4*)(feat + (size_t)b * 32);
#pragma unroll
  for (int q = 0; q < 8; ++q) {
    const float4 v = fp[q];
    f[q * 4 + 0] = v.x; f[q * 4 + 1] = v.y;
    f[q * 4 + 2] = v.z; f[q * 4 + 3] = v.w;
  }
  float m = -3.0e38f;
  float s = 0.f;
  for (int k = 0; k < 8; ++k) {           // rolled: keeps I$ small, L ptr uniform
    const float* __restrict__ L = cws + 8736 + k * 1024;
    const float* __restrict__ lm = cws + 8472 + k * 32;
    float mah = 0.f;
#pragma unroll
    for (int j = 0; j < 32; ++j) {
      float y = -lm[j];
#pragma unroll
      for (int p = 0; p <= j; ++p) y = fmaf(L[j * 32 + p], f[p], y);
      mah = fmaf(y, y, mah);
    }
    const float w = cws[8464 + k] - 0.5f * mah;
    const float mn = fmaxf(m, w);
    s = s * expf(m - mn) + expf(w - mn);  // online logsumexp
    m = mn;
  }
  float en = -(m + logf(s + 1e-10f));
  en = (en == en && en < 1e38f && en > -1e38f) ? en : 0.f;  // isfinite guard
  float rv = rec[b];
#pragma unroll
  for (int off = 32; off > 0; off >>= 1) {
    en += __shfl_down(en, off);
    rv += __shfl_down(rv, off);
  }
  if ((threadIdx.x & 63) == 0) {
    atomicAdd(aws + 8457, en);
    atomicAdd(aws + 8458, rv);
  }
}

__global__ void k_final(const float* __restrict__ ws, float* __restrict__ out) {
  if (threadIdx.x == 0) {
    const float recm = ws[8458] * (1.f / (float)B_SIZE);
    const float enm  = ws[8457] * (1.f / (float)B_SIZE);
    out[0] = recm + 0.1f * enm + 0.005f * ws[8456];
  }
}

extern "C" void kernel_launch(void* const* d_in, const int* in_sizes, int n_in,
                              void* d_out, int out_size, void* d_ws, size_t ws_size,
                              hipStream_t stream) {
  const float* gamma = (const float*)d_in[0];
  const float* feat  = (const float*)d_in[1];
  const float* rec   = (const float*)d_in[2];
  float* ws = (float*)d_ws;
  float* out = (float*)d_out;

  hipMemsetAsync(d_ws, 0, 8464 * sizeof(float), stream);
  hipLaunchKernelGGL(k_moments, dim3(NBLK_MOM), dim3(256), 0, stream, gamma, feat, ws);
  hipLaunchKernelGGL(k_prepare, dim3(1), dim3(256), 0, stream, ws);
  hipLaunchKernelGGL(k_energy, dim3(B_SIZE / 256), dim3(256), 0, stream, feat, rec, ws, ws);
  hipLaunchKernelGGL(k_final, dim3(1), dim3(64), 0, stream, ws, out);
}

// Round 3
// 352.362 us; speedup vs baseline: 1.2678x; 1.2678x over previous
//
#include <hip/hip_runtime.h>

using v8h  = __attribute__((ext_vector_type(8))) __fp16;
using h2   = __attribute__((ext_vector_type(2))) __fp16;
using v16f = __attribute__((ext_vector_type(16))) float;
using v4f  = __attribute__((ext_vector_type(4))) float;

#define B_SIZE 262144
// ws float offsets
#define WS_S2    0      // 8192 : S2[k][d][e]
#define WS_S1    8192   // 256  : S1[k][d]
#define WS_GS    8448   // 8    : gsum[k]
#define WS_SING  8456
#define WS_EN    8457
#define WS_REC   8458
#define WS_C1    8464   // 8    : log(phi+1e-10) - 0.5*(logdet + D log 2pi)
#define WS_LMU   8472   // 256  : (Linv_k mu_k)[j]
#define WS_L16   8736   // 4096 floats = 8192 halfs : Linv f16 [k][j][p]

union PkU { h2 p[4]; v8h v; };

// ---------------------------------------------------------------------------
// Kernel 1: raw moments via MFMA. S2[k] += A_k * B, A_k = (gamma_k ⊙ f)^T,
// B = f.  a_frag = gamma ⊙ b_frag elementwise (v_pk_mul_f16).
// 32x32x16 f16 layouts: A[m=lane&31][kk=(lane>>5)*8+j]; B[kk][n=lane&31];
// C/D: col=lane&31, row=(reg&3)+8*(reg>>2)+4*(lane>>5).
// ---------------------------------------------------------------------------
#define MOM_BLK 512
__global__ __launch_bounds__(256, 2) void k_moments(
    const float* __restrict__ gamma, const float* __restrict__ feat,
    float* __restrict__ ws) {
  __shared__ float s2l[8 * 32 * 33];  // stride 33: (row+col)%32 banks, 2-way free
  __shared__ float s1l[8 * 32];
  __shared__ float gsl[8];
  const int tid = threadIdx.x, lane = tid & 63, wv = tid >> 6;
  for (int t = tid; t < 8 * 32 * 33; t += 256) s2l[t] = 0.f;
  if (tid < 256) s1l[tid] = 0.f;
  if (tid < 8) gsl[tid] = 0.f;
  __syncthreads();

  const int c = lane & 31, half = lane >> 5;
  const int gw = blockIdx.x * 4 + wv;          // 0..2047
  const int ROWS = B_SIZE / (MOM_BLK * 4);     // 128 rows/wave, 8 chunks of 16
  const int base = gw * ROWS;

  v16f acc[8];
#pragma unroll
  for (int k = 0; k < 8; ++k)
#pragma unroll
    for (int r = 0; r < 16; ++r) acc[k][r] = 0.f;
  float s1a[8] = {0, 0, 0, 0, 0, 0, 0, 0};
  float ga[8]  = {0, 0, 0, 0, 0, 0, 0, 0};

  for (int ch = 0; ch < ROWS / 16; ++ch) {
    const int rb = base + ch * 16 + half * 8;  // this half-wave's 8 rows
    float fc[8];
#pragma unroll
    for (int j = 0; j < 8; ++j) fc[j] = feat[(size_t)(rb + j) * 32 + c];
    PkU fp;
#pragma unroll
    for (int jj = 0; jj < 4; ++jj)
      fp.p[jj] = __builtin_amdgcn_cvt_pkrtz(fc[2 * jj], fc[2 * jj + 1]);

    PkU gp[8];
#pragma unroll
    for (int jj = 0; jj < 4; ++jj) {
      const float4 a0 = *(const float4*)(gamma + (size_t)(rb + 2 * jj) * 8);
      const float4 a1 = *(const float4*)(gamma + (size_t)(rb + 2 * jj) * 8 + 4);
      const float4 b0 = *(const float4*)(gamma + (size_t)(rb + 2 * jj + 1) * 8);
      const float4 b1 = *(const float4*)(gamma + (size_t)(rb + 2 * jj + 1) * 8 + 4);
      const float gr0[8] = {a0.x, a0.y, a0.z, a0.w, a1.x, a1.y, a1.z, a1.w};
      const float gr1[8] = {b0.x, b0.y, b0.z, b0.w, b1.x, b1.y, b1.z, b1.w};
#pragma unroll
      for (int k = 0; k < 8; ++k) {
        gp[k].p[jj] = __builtin_amdgcn_cvt_pkrtz(gr0[k], gr1[k]);
        s1a[k] = fmaf(gr0[k], fc[2 * jj], fmaf(gr1[k], fc[2 * jj + 1], s1a[k]));
        ga[k] += gr0[k] + gr1[k];
      }
    }
#pragma unroll
    for (int k = 0; k < 8; ++k) {
      const v8h af = gp[k].v * fp.v;   // v_pk_mul_f16: gamma_k ⊙ f
      acc[k] = __builtin_amdgcn_mfma_f32_32x32x16_f16(af, fp.v, acc[k], 0, 0, 0);
    }
  }

  // block-level LDS accumulation
#pragma unroll
  for (int k = 0; k < 8; ++k)
#pragma unroll
    for (int r = 0; r < 16; ++r) {
      const int row = (r & 3) + 8 * (r >> 2) + 4 * half;
      atomicAdd(&s2l[k * 1056 + row * 33 + c], acc[k][r]);
    }
#pragma unroll
  for (int k = 0; k < 8; ++k) atomicAdd(&s1l[k * 32 + c], s1a[k]);
#pragma unroll
  for (int k = 0; k < 8; ++k) {  // each row counted by 32 lanes -> /32
    float v = ga[k];
#pragma unroll
    for (int m = 32; m; m >>= 1) v += __shfl_down(v, m);
    if (lane == 0) atomicAdd(&gsl[k], v * (1.f / 32.f));
  }
  __syncthreads();

  for (int t = tid; t < 8192; t += 256) {
    const int k = t >> 10, row = (t >> 5) & 31, cc = t & 31;
    atomicAdd(&ws[WS_S2 + t], s2l[k * 1056 + row * 33 + cc]);
  }
  if (tid < 256) atomicAdd(&ws[WS_S1 + tid], s1l[tid]);
  if (tid < 8) atomicAdd(&ws[WS_GS + tid], gsl[tid]);
}

// ---------------------------------------------------------------------------
// Kernel 2: sigma assembly, Cholesky, Linv (f32 LDS -> f16 ws), logdet, c1,
// lmu, singularity. One block, 8 groups x 32 lanes.
// ---------------------------------------------------------------------------
__global__ void k_prepare(float* __restrict__ ws) {
  __shared__ float A[8][32][33];
  __shared__ float Lv[8][32][33];
  __shared__ float mu_s[8][32];
  __shared__ float red[256];
  const int tid = threadIdx.x;
  const int k = tid >> 5;
  const int i = tid & 31;

  const float gs = ws[WS_GS + k];
  const float denom = gs + 1e-8f;
  const float s1i = ws[WS_S1 + k * 32 + i];
  const float mu_i = s1i / denom;
  mu_s[k][i] = mu_i;
  __syncthreads();

  float sing = 0.f;
  for (int j = 0; j < 32; ++j) {
    const float s2 = ws[WS_S2 + k * 1024 + i * 32 + j];
    const float muj = mu_s[k][j];
    const float s1j = ws[WS_S1 + k * 32 + j];
    const float num = s2 - mu_i * s1j - muj * s1i + gs * mu_i * muj;
    const float sig = num / denom + ((i == j) ? 1e-6f : 0.f);
    A[k][i][j] = sig;
    if (i == j) sing = 1.f / (sig + 1e-8f);
  }
  red[tid] = sing;
  __syncthreads();
  for (int s = 128; s > 0; s >>= 1) {      // parallel tree (was serial 256-loop)
    if (tid < s) red[tid] += red[tid + s];
    __syncthreads();
  }
  if (tid == 0) ws[WS_SING] = red[0];
  __syncthreads();

  // right-looking Cholesky in place
  for (int j = 0; j < 32; ++j) {
    const float ljj = sqrtf(A[k][j][j]);
    float lij;
    if (i == j)      lij = ljj;
    else if (i > j)  lij = A[k][i][j] / ljj;
    else             lij = 0.f;
    A[k][i][j] = lij;
    __syncthreads();
    for (int p = j + 1; p < 32; ++p) {
      const float lpj = A[k][p][j];
      if (p <= i) A[k][i][p] -= lij * lpj;
    }
    __syncthreads();
  }

  // forward substitution: lane i -> column i of Linv
  float x[32];
#pragma unroll
  for (int r = 0; r < 32; ++r) {
    float s = (r == i) ? 1.f : 0.f;
#pragma unroll
    for (int p = 0; p < r; ++p) s -= A[k][r][p] * x[p];
    x[r] = s / A[k][r][r];
  }
#pragma unroll
  for (int r = 0; r < 32; ++r) Lv[k][r][i] = x[r];
  __syncthreads();

  // row-major f16 Linv for k_energy B-fragments
  __fp16* l16 = (__fp16*)(ws + WS_L16);
  for (int p = 0; p < 32; ++p)
    l16[k * 1024 + i * 32 + p] = (__fp16)Lv[k][i][p];

  // lmu
  float lm = 0.f;
  for (int p = 0; p < 32; ++p) lm += Lv[k][i][p] * mu_s[k][p];
  ws[WS_LMU + k * 32 + i] = lm;

  red[tid] = logf(A[k][i][i]);
  __syncthreads();
  if (i == 0) {
    float ld = 0.f;
    for (int t = 0; t < 32; ++t) ld += red[k * 32 + t];
    ld *= 2.f;
    const float phi = gs * (1.f / (float)B_SIZE);
    ws[WS_C1 + k] = logf(phi + 1e-10f) - 0.5f * (ld + 32.f * logf(6.28318f));
  }
}

// ---------------------------------------------------------------------------
// Kernel 3: Y = F * M^T via 16x16x32 f16 MFMA (M = stacked Linv, 256x32),
// mahal = sum over j of (Y - lmu)^2 (butterfly over 16-lane col group),
// online logsumexp, energy + recon reduction.
// 16x16x32 layouts: A[m=lane&15][p=(lane>>4)*8+j]; B[p][n=lane&15];
// C/D: col=lane&15, row=(lane>>4)*4+reg.
// ---------------------------------------------------------------------------
#define EN_BLK 512
__global__ __launch_bounds__(256, 2) void k_energy(
    const float* __restrict__ feat, const float* __restrict__ rec,
    const float* __restrict__ ws, float* __restrict__ aws) {
  const int tid = threadIdx.x, lane = tid & 63, wv = tid >> 6;
  const int gw = blockIdx.x * 4 + wv;          // 0..2047
  const int ROWS = B_SIZE / (EN_BLK * 4);      // 128
  const int base = gw * ROWS;
  const int cl = lane & 15, g = lane >> 4;     // g in 0..3
  const int p0 = g * 8;

  const __fp16* l16 = (const __fp16*)(ws + WS_L16);
  v8h bf[16];
  float lmu[16];
#pragma unroll
  for (int t = 0; t < 16; ++t) {
    const int col = t * 16 + cl, k = col >> 5, j = col & 31;
    bf[t] = *(const v8h*)(l16 + k * 1024 + j * 32 + p0);
    lmu[t] = ws[WS_LMU + col];
  }
  float c1[8];
#pragma unroll
  for (int k = 0; k < 8; ++k) c1[k] = ws[WS_C1 + k];

  float en_acc = 0.f, rv_acc = 0.f;
  const v4f zf = {0.f, 0.f, 0.f, 0.f};

  for (int ch = 0; ch < ROWS / 16; ++ch) {
    const int b0 = base + ch * 16;
    const size_t row = (size_t)(b0 + cl) * 32;
    const float4 fa = *(const float4*)(feat + row + p0);
    const float4 fb = *(const float4*)(feat + row + p0 + 4);
    PkU af;
    af.p[0] = __builtin_amdgcn_cvt_pkrtz(fa.x, fa.y);
    af.p[1] = __builtin_amdgcn_cvt_pkrtz(fa.z, fa.w);
    af.p[2] = __builtin_amdgcn_cvt_pkrtz(fb.x, fb.y);
    af.p[3] = __builtin_amdgcn_cvt_pkrtz(fb.z, fb.w);

    float zk[8][4];
#pragma unroll
    for (int k = 0; k < 8; ++k)
#pragma unroll
      for (int r = 0; r < 4; ++r) zk[k][r] = 0.f;

#pragma unroll
    for (int t = 0; t < 16; ++t) {
      const v4f y = __builtin_amdgcn_mfma_f32_16x16x32_f16(af.v, bf[t], zf, 0, 0, 0);
      const int k = t >> 1;
#pragma unroll
      for (int r = 0; r < 4; ++r) {
        const float v = y[r] - lmu[t];
        zk[k][r] = fmaf(v, v, zk[k][r]);
      }
    }
#pragma unroll
    for (int m = 1; m < 16; m <<= 1)
#pragma unroll
      for (int k = 0; k < 8; ++k)
#pragma unroll
        for (int r = 0; r < 4; ++r) zk[k][r] += __shfl_xor(zk[k][r], m);

    if (cl < 4) {  // lane cl handles local row 4g+cl (reg index cl)
      float mx = -3.0e38f, s = 0.f;
#pragma unroll
      for (int k = 0; k < 8; ++k) {
        const float w = c1[k] - 0.5f * zk[k][cl];
        const float mn = fmaxf(mx, w);
        s = s * __expf(mx - mn) + __expf(w - mn);
        mx = mn;
      }
      float en = -(mx + __logf(s + 1e-10f));
      en = (en == en && en < 1e38f && en > -1e38f) ? en : 0.f;
      en_acc += en;
    }
    if (lane < 16) rv_acc += rec[b0 + lane];
  }
#pragma unroll
  for (int m = 32; m; m >>= 1) {
    en_acc += __shfl_down(en_acc, m);
    rv_acc += __shfl_down(rv_acc, m);
  }
  if (lane == 0) {
    atomicAdd(aws + WS_EN, en_acc);
    atomicAdd(aws + WS_REC, rv_acc);
  }
}

__global__ void k_final(const float* __restrict__ ws, float* __restrict__ out) {
  if (threadIdx.x == 0) {
    const float recm = ws[WS_REC] * (1.f / (float)B_SIZE);
    const float enm  = ws[WS_EN]  * (1.f / (float)B_SIZE);
    out[0] = recm + 0.1f * enm + 0.005f * ws[WS_SING];
  }
}

extern "C" void kernel_launch(void* const* d_in, const int* in_sizes, int n_in,
                              void* d_out, int out_size, void* d_ws, size_t ws_size,
                              hipStream_t stream) {
  const float* gamma = (const float*)d_in[0];
  const float* feat  = (const float*)d_in[1];
  const float* rec   = (const float*)d_in[2];
  float* ws = (float*)d_ws;
  float* out = (float*)d_out;

  (void)hipMemsetAsync(d_ws, 0, 8464 * sizeof(float), stream);
  hipLaunchKernelGGL(k_moments, dim3(MOM_BLK), dim3(256), 0, stream, gamma, feat, ws);
  hipLaunchKernelGGL(k_prepare, dim3(1), dim3(256), 0, stream, ws);
  hipLaunchKernelGGL(k_energy, dim3(EN_BLK), dim3(256), 0, stream, feat, rec, ws, ws);
  hipLaunchKernelGGL(k_final, dim3(1), dim3(64), 0, stream, ws, out);
}

// Round 4
// 329.763 us; speedup vs baseline: 1.3547x; 1.0685x over previous
//
#include <hip/hip_runtime.h>

using v8h  = __attribute__((ext_vector_type(8))) __fp16;
using h2   = __attribute__((ext_vector_type(2))) __fp16;
using v16f = __attribute__((ext_vector_type(16))) float;
using v4f  = __attribute__((ext_vector_type(4))) float;

#define B_SIZE 262144
// ws float offsets
#define WS_S2    0       // 8192 : S2[k][d][e]
#define WS_S1    8192    // 256  : S1[k][d]
#define WS_GS    8448    // 8    : gsum[k]
#define WS_SING  8456
#define WS_C1    8464    // 8
#define WS_LMU   8472    // 256
#define WS_L16   8736    // 4096 floats = 8192 halfs : Linv f16 [k][j][p]
#define WS_ENP   13056   // 1024 energy partials
#define WS_RCP   14080   // 1024 recon partials
#define WS_PART  15360   // 256 x 8464 moment partials (8.7 MB)
#define PART_STRIDE 8464
#define MOM_BLK  256     // 512-thread blocks
#define EN_BLK   1024    // 256-thread blocks

union PkU { h2 p[4]; v8h v; };

// ---------------------------------------------------------------------------
// Kernel 1: raw moments via MFMA; block partial -> part[blk] (NO global atomics)
// ---------------------------------------------------------------------------
__global__ __launch_bounds__(512, 2) void k_moments(
    const float* __restrict__ gamma, const float* __restrict__ feat,
    float* __restrict__ part) {
  __shared__ float s2l[8 * 32 * 33];  // stride 33: 2-way banks (free)
  __shared__ float s1l[8 * 32];
  __shared__ float gsl[8];
  const int tid = threadIdx.x, lane = tid & 63, wv = tid >> 6;
  for (int t = tid; t < 8 * 32 * 33; t += 512) s2l[t] = 0.f;
  if (tid < 256) s1l[tid] = 0.f;
  if (tid < 8) gsl[tid] = 0.f;
  __syncthreads();

  const int c = lane & 31, half = lane >> 5;
  const int gw = blockIdx.x * 8 + wv;          // 0..2047
  const int ROWS = B_SIZE / (MOM_BLK * 8);     // 128 rows/wave
  const int base = gw * ROWS;

  v16f acc[8];
#pragma unroll
  for (int k = 0; k < 8; ++k)
#pragma unroll
    for (int r = 0; r < 16; ++r) acc[k][r] = 0.f;
  float s1a[8] = {0, 0, 0, 0, 0, 0, 0, 0};
  float ga[8]  = {0, 0, 0, 0, 0, 0, 0, 0};

  for (int ch = 0; ch < ROWS / 16; ++ch) {
    const int rb = base + ch * 16 + half * 8;
    float fc[8];
#pragma unroll
    for (int j = 0; j < 8; ++j) fc[j] = feat[(size_t)(rb + j) * 32 + c];
    PkU fp;
#pragma unroll
    for (int jj = 0; jj < 4; ++jj)
      fp.p[jj] = __builtin_amdgcn_cvt_pkrtz(fc[2 * jj], fc[2 * jj + 1]);

    PkU gp[8];
#pragma unroll
    for (int jj = 0; jj < 4; ++jj) {
      const float4 a0 = *(const float4*)(gamma + (size_t)(rb + 2 * jj) * 8);
      const float4 a1 = *(const float4*)(gamma + (size_t)(rb + 2 * jj) * 8 + 4);
      const float4 b0 = *(const float4*)(gamma + (size_t)(rb + 2 * jj + 1) * 8);
      const float4 b1 = *(const float4*)(gamma + (size_t)(rb + 2 * jj + 1) * 8 + 4);
      const float gr0[8] = {a0.x, a0.y, a0.z, a0.w, a1.x, a1.y, a1.z, a1.w};
      const float gr1[8] = {b0.x, b0.y, b0.z, b0.w, b1.x, b1.y, b1.z, b1.w};
#pragma unroll
      for (int k = 0; k < 8; ++k) {
        gp[k].p[jj] = __builtin_amdgcn_cvt_pkrtz(gr0[k], gr1[k]);
        s1a[k] = fmaf(gr0[k], fc[2 * jj], fmaf(gr1[k], fc[2 * jj + 1], s1a[k]));
        ga[k] += gr0[k] + gr1[k];
      }
    }
#pragma unroll
    for (int k = 0; k < 8; ++k) {
      const v8h af = gp[k].v * fp.v;   // gamma_k ⊙ f
      acc[k] = __builtin_amdgcn_mfma_f32_32x32x16_f16(af, fp.v, acc[k], 0, 0, 0);
    }
  }

  // block-level LDS accumulation (LDS atomics only)
#pragma unroll
  for (int k = 0; k < 8; ++k)
#pragma unroll
    for (int r = 0; r < 16; ++r) {
      const int row = (r & 3) + 8 * (r >> 2) + 4 * half;
      atomicAdd(&s2l[k * 1056 + row * 33 + c], acc[k][r]);
    }
#pragma unroll
  for (int k = 0; k < 8; ++k) atomicAdd(&s1l[k * 32 + c], s1a[k]);
#pragma unroll
  for (int k = 0; k < 8; ++k) {
    float v = ga[k];
#pragma unroll
    for (int m = 32; m; m >>= 1) v += __shfl_down(v, m);
    if (lane == 0) atomicAdd(&gsl[k], v * (1.f / 32.f));
  }
  __syncthreads();

  // streaming partial store (no atomics)
  float* pb = part + (size_t)blockIdx.x * PART_STRIDE;
  for (int t = tid; t < 8192; t += 512) {
    const int k = t >> 10, row = (t >> 5) & 31, cc = t & 31;
    pb[t] = s2l[k * 1056 + row * 33 + cc];
  }
  if (tid < 256) pb[8192 + tid] = s1l[tid];
  if (tid < 8) pb[8448 + tid] = gsl[tid];
}

// ---------------------------------------------------------------------------
// Kernel 1b: deterministic partial reduction. thread t owns entry t.
// ---------------------------------------------------------------------------
__global__ void k_reduce(const float* __restrict__ part, float* __restrict__ ws) {
  const int t = blockIdx.x * 256 + threadIdx.x;
  if (t >= 8456) return;
  float s = 0.f;
  for (int b = 0; b < MOM_BLK; ++b) s += part[(size_t)b * PART_STRIDE + t];
  ws[t] = s;   // S2 / S1 / GS at their final offsets
}

// ---------------------------------------------------------------------------
// Kernel 2: sigma, Cholesky, Linv->f16, logdet, c1, lmu, singularity.
// ---------------------------------------------------------------------------
__global__ void k_prepare(float* __restrict__ ws) {
  __shared__ float A[8][32][33];
  __shared__ float Lv[8][32][33];
  __shared__ float mu_s[8][32];
  __shared__ float red[256];
  const int tid = threadIdx.x;
  const int k = tid >> 5;
  const int i = tid & 31;

  const float gs = ws[WS_GS + k];
  const float denom = gs + 1e-8f;
  const float s1i = ws[WS_S1 + k * 32 + i];
  const float mu_i = s1i / denom;
  mu_s[k][i] = mu_i;
  __syncthreads();

  float sing = 0.f;
  for (int j = 0; j < 32; ++j) {
    const float s2 = ws[WS_S2 + k * 1024 + i * 32 + j];
    const float muj = mu_s[k][j];
    const float s1j = ws[WS_S1 + k * 32 + j];
    const float num = s2 - mu_i * s1j - muj * s1i + gs * mu_i * muj;
    const float sig = num / denom + ((i == j) ? 1e-6f : 0.f);
    A[k][i][j] = sig;
    if (i == j) sing = 1.f / (sig + 1e-8f);
  }
  red[tid] = sing;
  __syncthreads();
  for (int s = 128; s > 0; s >>= 1) {
    if (tid < s) red[tid] += red[tid + s];
    __syncthreads();
  }
  if (tid == 0) ws[WS_SING] = red[0];
  __syncthreads();

  for (int j = 0; j < 32; ++j) {
    const float ljj = sqrtf(A[k][j][j]);
    float lij;
    if (i == j)      lij = ljj;
    else if (i > j)  lij = A[k][i][j] / ljj;
    else             lij = 0.f;
    A[k][i][j] = lij;
    __syncthreads();
    for (int p = j + 1; p < 32; ++p) {
      const float lpj = A[k][p][j];
      if (p <= i) A[k][i][p] -= lij * lpj;
    }
    __syncthreads();
  }

  float x[32];
#pragma unroll
  for (int r = 0; r < 32; ++r) {
    float s = (r == i) ? 1.f : 0.f;
#pragma unroll
    for (int p = 0; p < r; ++p) s -= A[k][r][p] * x[p];
    x[r] = s / A[k][r][r];
  }
#pragma unroll
  for (int r = 0; r < 32; ++r) Lv[k][r][i] = x[r];
  __syncthreads();

  __fp16* l16 = (__fp16*)(ws + WS_L16);
  for (int p = 0; p < 32; ++p)
    l16[k * 1024 + i * 32 + p] = (__fp16)Lv[k][i][p];

  float lm = 0.f;
  for (int p = 0; p < 32; ++p) lm += Lv[k][i][p] * mu_s[k][p];
  ws[WS_LMU + k * 32 + i] = lm;

  red[tid] = logf(A[k][i][i]);
  __syncthreads();
  if (i == 0) {
    float ld = 0.f;
    for (int t = 0; t < 32; ++t) ld += red[k * 32 + t];
    ld *= 2.f;
    const float phi = gs * (1.f / (float)B_SIZE);
    ws[WS_C1 + k] = logf(phi + 1e-10f) - 0.5f * (ld + 32.f * logf(6.28318f));
  }
}

// ---------------------------------------------------------------------------
// Kernel 3: mahalanobis via 16x16x32 f16 MFMA + butterfly + online LSE.
// Block partial -> ENP/RCP arrays (no global atomics).
// ---------------------------------------------------------------------------
__global__ __launch_bounds__(256, 4) void k_energy(
    const float* __restrict__ feat, const float* __restrict__ rec,
    const float* __restrict__ ws, float* __restrict__ aws) {
  __shared__ float ben[4], brc[4];
  const int tid = threadIdx.x, lane = tid & 63, wv = tid >> 6;
  const int gw = blockIdx.x * 4 + wv;          // 0..4095
  const int ROWS = B_SIZE / (EN_BLK * 4);      // 64
  const int base = gw * ROWS;
  const int cl = lane & 15, g = lane >> 4;
  const int p0 = g * 8;

  const __fp16* l16 = (const __fp16*)(ws + WS_L16);
  v8h bf[16];
  float lmu[16];
#pragma unroll
  for (int t = 0; t < 16; ++t) {
    const int col = t * 16 + cl, k = col >> 5, j = col & 31;
    bf[t] = *(const v8h*)(l16 + k * 1024 + j * 32 + p0);
    lmu[t] = ws[WS_LMU + col];
  }
  float c1[8];
#pragma unroll
  for (int k = 0; k < 8; ++k) c1[k] = ws[WS_C1 + k];

  float en_acc = 0.f, rv_acc = 0.f;
  const v4f zf = {0.f, 0.f, 0.f, 0.f};

  for (int ch = 0; ch < ROWS / 16; ++ch) {
    const int b0 = base + ch * 16;
    const size_t row = (size_t)(b0 + cl) * 32;
    const float4 fa = *(const float4*)(feat + row + p0);
    const float4 fb = *(const float4*)(feat + row + p0 + 4);
    PkU af;
    af.p[0] = __builtin_amdgcn_cvt_pkrtz(fa.x, fa.y);
    af.p[1] = __builtin_amdgcn_cvt_pkrtz(fa.z, fa.w);
    af.p[2] = __builtin_amdgcn_cvt_pkrtz(fb.x, fb.y);
    af.p[3] = __builtin_amdgcn_cvt_pkrtz(fb.z, fb.w);

    float zk[8][4];
#pragma unroll
    for (int k = 0; k < 8; ++k)
#pragma unroll
      for (int r = 0; r < 4; ++r) zk[k][r] = 0.f;

#pragma unroll
    for (int t = 0; t < 16; ++t) {
      const v4f y = __builtin_amdgcn_mfma_f32_16x16x32_f16(af.v, bf[t], zf, 0, 0, 0);
      const int k = t >> 1;
#pragma unroll
      for (int r = 0; r < 4; ++r) {
        const float v = y[r] - lmu[t];
        zk[k][r] = fmaf(v, v, zk[k][r]);
      }
    }
#pragma unroll
    for (int m = 1; m < 16; m <<= 1)
#pragma unroll
      for (int k = 0; k < 8; ++k)
#pragma unroll
        for (int r = 0; r < 4; ++r) zk[k][r] += __shfl_xor(zk[k][r], m);

    if (cl < 4) {
      float mx = -3.0e38f, s = 0.f;
#pragma unroll
      for (int k = 0; k < 8; ++k) {
        const float w = c1[k] - 0.5f * zk[k][cl];
        const float mn = fmaxf(mx, w);
        s = s * __expf(mx - mn) + __expf(w - mn);
        mx = mn;
      }
      float en = -(mx + __logf(s + 1e-10f));
      en = (en == en && en < 1e38f && en > -1e38f) ? en : 0.f;
      en_acc += en;
    }
    if (lane < 16) rv_acc += rec[b0 + lane];
  }
#pragma unroll
  for (int m = 32; m; m >>= 1) {
    en_acc += __shfl_down(en_acc, m);
    rv_acc += __shfl_down(rv_acc, m);
  }
  if (lane == 0) { ben[wv] = en_acc; brc[wv] = rv_acc; }
  __syncthreads();
  if (tid == 0) {
    aws[WS_ENP + blockIdx.x] = ben[0] + ben[1] + ben[2] + ben[3];
    aws[WS_RCP + blockIdx.x] = brc[0] + brc[1] + brc[2] + brc[3];
  }
}

// ---------------------------------------------------------------------------
// Kernel 4: final deterministic reduction of 1024 partials + combine.
// ---------------------------------------------------------------------------
__global__ void k_final(const float* __restrict__ ws, float* __restrict__ out) {
  __shared__ float r1[256], r2[256];
  const int tid = threadIdx.x;
  float e = 0.f, r = 0.f;
  for (int i = tid; i < EN_BLK; i += 256) {
    e += ws[WS_ENP + i];
    r += ws[WS_RCP + i];
  }
  r1[tid] = e; r2[tid] = r;
  __syncthreads();
  for (int s = 128; s > 0; s >>= 1) {
    if (tid < s) { r1[tid] += r1[tid + s]; r2[tid] += r2[tid + s]; }
    __syncthreads();
  }
  if (tid == 0) {
    const float recm = r2[0] * (1.f / (float)B_SIZE);
    const float enm  = r1[0] * (1.f / (float)B_SIZE);
    out[0] = recm + 0.1f * enm + 0.005f * ws[WS_SING];
  }
}

extern "C" void kernel_launch(void* const* d_in, const int* in_sizes, int n_in,
                              void* d_out, int out_size, void* d_ws, size_t ws_size,
                              hipStream_t stream) {
  const float* gamma = (const float*)d_in[0];
  const float* feat  = (const float*)d_in[1];
  const float* rec   = (const float*)d_in[2];
  float* ws = (float*)d_ws;
  float* out = (float*)d_out;

  hipLaunchKernelGGL(k_moments, dim3(MOM_BLK), dim3(512), 0, stream,
                     gamma, feat, ws + WS_PART);
  hipLaunchKernelGGL(k_reduce, dim3(34), dim3(256), 0, stream, ws + WS_PART, ws);
  hipLaunchKernelGGL(k_prepare, dim3(1), dim3(256), 0, stream, ws);
  hipLaunchKernelGGL(k_energy, dim3(EN_BLK), dim3(256), 0, stream, feat, rec, ws, ws);
  hipLaunchKernelGGL(k_final, dim3(1), dim3(256), 0, stream, ws, out);
}

// Round 5
// 187.831 us; speedup vs baseline: 2.3784x; 1.7556x over previous
//
#include <hip/hip_runtime.h>

using v8h  = __attribute__((ext_vector_type(8))) __fp16;
using h2   = __attribute__((ext_vector_type(2))) __fp16;
using v16f = __attribute__((ext_vector_type(16))) float;
using v4f  = __attribute__((ext_vector_type(4))) float;

#define B_SIZE 262144
// ws float offsets
#define WS_S2    0       // 8192 : S2[k][d][e]
#define WS_S1    8192    // 256  : S1[k][d]
#define WS_GS    8448    // 8    : gsum[k]
#define WS_SING  8456
#define WS_C1    8464    // 8 : log(phi)-0.5(logdet+Dlog2pi+|lmu|^2)
#define WS_L16   8736    // 4352 floats = 8704 halfs : M' [272 rows][32] f16
                         //   rows 0..255 Linv (k*32+j), 256..263 q_k, 264..271 zero
#define WS_ENP   13184   // 1024 energy partials
#define WS_RCP   14208   // 1024 recon partials
#define WS_PART  15360   // 256 x 8464 moment partials (8.7 MB)
#define PART_STRIDE 8464
#define MOM_BLK  256     // 512-thread blocks, 1024 rows each
#define EN_BLK   1024    // 256-thread blocks

union PkU { h2 p[4]; v8h v; };

// ---------------------------------------------------------------------------
// Kernel 1: raw moments. ONE k PER WAVE (8 waves/block): acc = 16 VGPRs,
// no spill, no LDS atomics (per-wave exclusive tile), no global atomics.
// 32x32x16 layouts: A[m=lane&31][kk=(lane>>5)*8+j]; B[kk][n=lane&31];
// C/D: col=lane&31, row=(reg&3)+8*(reg>>2)+4*(lane>>5).
// ---------------------------------------------------------------------------
__global__ __launch_bounds__(512, 4) void k_moments(
    const float* __restrict__ gamma, const float* __restrict__ feat,
    float* __restrict__ part) {
  __shared__ float s2l[8 * 32 * 33];
  __shared__ float s1l[8 * 32];
  __shared__ float gsl[8];
  const int tid = threadIdx.x, lane = tid & 63, w = tid >> 6;  // w == k
  const int c = lane & 31, half = lane >> 5;
  const int ROWS = B_SIZE / MOM_BLK;           // 1024
  const int base = blockIdx.x * ROWS;

  v16f acc;
#pragma unroll
  for (int r = 0; r < 16; ++r) acc[r] = 0.f;
  float s1a = 0.f, ga = 0.f;

  for (int ch = 0; ch < ROWS / 16; ++ch) {     // 64 chunks of 16 rows
    const int rb = base + ch * 16 + half * 8;
    float fc[8], g8[8];
#pragma unroll
    for (int j = 0; j < 8; ++j) {
      fc[j] = feat[(size_t)(rb + j) * 32 + c];
      g8[j] = gamma[(size_t)(rb + j) * 8 + w]; // broadcast (uniform per half)
    }
    PkU fp, gp;
#pragma unroll
    for (int jj = 0; jj < 4; ++jj) {
      fp.p[jj] = __builtin_amdgcn_cvt_pkrtz(fc[2 * jj], fc[2 * jj + 1]);
      gp.p[jj] = __builtin_amdgcn_cvt_pkrtz(g8[2 * jj], g8[2 * jj + 1]);
    }
#pragma unroll
    for (int j = 0; j < 8; ++j) {
      s1a = fmaf(g8[j], fc[j], s1a);
      ga += g8[j];
    }
    const v8h af = gp.v * fp.v;                // gamma_k ⊙ f
    acc = __builtin_amdgcn_mfma_f32_32x32x16_f16(af, fp.v, acc, 0, 0, 0);
  }

  // per-wave exclusive LDS tile: plain stores
#pragma unroll
  for (int r = 0; r < 16; ++r) {
    const int row = (r & 3) + 8 * (r >> 2) + 4 * half;
    s2l[w * 1056 + row * 33 + c] = acc[r];
  }
  s1a += __shfl_xor(s1a, 32);                  // combine halves
  ga  += __shfl_xor(ga, 32);
  if (half == 0) s1l[w * 32 + c] = s1a;
  if (lane == 0) gsl[w] = ga;
  __syncthreads();

  float* pb = part + (size_t)blockIdx.x * PART_STRIDE;
  for (int t = tid; t < 8192; t += 512) {
    const int k = t >> 10, row = (t >> 5) & 31, cc = t & 31;
    pb[t] = s2l[k * 1056 + row * 33 + cc];
  }
  if (tid < 256) pb[8192 + tid] = s1l[tid];
  if (tid < 8) pb[8448 + tid] = gsl[tid];
}

// ---------------------------------------------------------------------------
// Kernel 1b: deterministic partial reduction.
// ---------------------------------------------------------------------------
__global__ void k_reduce(const float* __restrict__ part, float* __restrict__ ws) {
  const int t = blockIdx.x * 256 + threadIdx.x;
  if (t >= 8456) return;
  float s = 0.f;
  for (int b = 0; b < MOM_BLK; ++b) s += part[(size_t)b * PART_STRIDE + t];
  ws[t] = s;
}

// ---------------------------------------------------------------------------
// Kernel 2: sigma, Cholesky, Linv->f16 M' rows, q_k = Linv^T lmu, c1.
// ---------------------------------------------------------------------------
__global__ void k_prepare(float* __restrict__ ws) {
  __shared__ float A[8][32][33];
  __shared__ float Lv[8][32][33];
  __shared__ float mu_s[8][32];
  __shared__ float lmu_sh[8][32];
  __shared__ float red[256];
  const int tid = threadIdx.x;
  const int k = tid >> 5;
  const int i = tid & 31;

  const float gs = ws[WS_GS + k];
  const float denom = gs + 1e-8f;
  const float s1i = ws[WS_S1 + k * 32 + i];
  const float mu_i = s1i / denom;
  mu_s[k][i] = mu_i;
  __syncthreads();

  float sing = 0.f;
  for (int j = 0; j < 32; ++j) {
    const float s2 = ws[WS_S2 + k * 1024 + i * 32 + j];
    const float muj = mu_s[k][j];
    const float s1j = ws[WS_S1 + k * 32 + j];
    const float num = s2 - mu_i * s1j - muj * s1i + gs * mu_i * muj;
    const float sig = num / denom + ((i == j) ? 1e-6f : 0.f);
    A[k][i][j] = sig;
    if (i == j) sing = 1.f / (sig + 1e-8f);
  }
  red[tid] = sing;
  __syncthreads();
  for (int s = 128; s > 0; s >>= 1) {
    if (tid < s) red[tid] += red[tid + s];
    __syncthreads();
  }
  if (tid == 0) ws[WS_SING] = red[0];
  __syncthreads();

  for (int j = 0; j < 32; ++j) {
    const float ljj = sqrtf(A[k][j][j]);
    float lij;
    if (i == j)      lij = ljj;
    else if (i > j)  lij = A[k][i][j] / ljj;
    else             lij = 0.f;
    A[k][i][j] = lij;
    __syncthreads();
    for (int p = j + 1; p < 32; ++p) {
      const float lpj = A[k][p][j];
      if (p <= i) A[k][i][p] -= lij * lpj;
    }
    __syncthreads();
  }

  float x[32];
#pragma unroll
  for (int r = 0; r < 32; ++r) {
    float s = (r == i) ? 1.f : 0.f;
#pragma unroll
    for (int p = 0; p < r; ++p) s -= A[k][r][p] * x[p];
    x[r] = s / A[k][r][r];
  }
#pragma unroll
  for (int r = 0; r < 32; ++r) Lv[k][r][i] = x[r];
  __syncthreads();

  __fp16* l16 = (__fp16*)(ws + WS_L16);
  for (int p = 0; p < 32; ++p)
    l16[(k * 32 + i) * 32 + p] = (__fp16)Lv[k][i][p];

  // lmu, |lmu|^2 (shuffle within 32-lane group), q = Linv^T lmu
  float lm = 0.f;
  for (int p = 0; p < 32; ++p) lm += Lv[k][i][p] * mu_s[k][p];
  float lm2 = lm * lm;
#pragma unroll
  for (int m = 1; m < 32; m <<= 1) lm2 += __shfl_xor(lm2, m);
  lmu_sh[k][i] = lm;
  __syncthreads();
  float q = 0.f;
  for (int j = 0; j < 32; ++j) q += Lv[k][j][i] * lmu_sh[k][j];
  l16[(256 + k) * 32 + i] = (__fp16)q;
  if (tid < 256) l16[(264 + (tid >> 5)) * 32 + (tid & 31)] = (__fp16)0.f;

  red[tid] = logf(A[k][i][i]);
  __syncthreads();
  if (i == 0) {
    float ld = 0.f;
    for (int t = 0; t < 32; ++t) ld += red[k * 32 + t];
    ld *= 2.f;
    const float phi = gs * (1.f / (float)B_SIZE);
    ws[WS_C1 + k] =
        logf(phi + 1e-10f) - 0.5f * (ld + 32.f * logf(6.28318f)) - 0.5f * lm2;
  }
}

// ---------------------------------------------------------------------------
// Kernel 3: Y = M' F^T via 16x16x32 MFMA (M' as A operand: 17 row-tiles incl
// q rows). mahal = |y|^2 - 2 f.q_k + |lmu_k|^2 -> w = c1' + y'_k - 0.5|y|^2.
// Only 2 shfl_xor rounds (over g groups) + 8 bpermutes per chunk.
// A[m=lane&15][d=(lane>>4)*8+j]; B[d][n=lane&15]; C/D col=lane&15,
// row=(lane>>4)*4+reg.
// ---------------------------------------------------------------------------
__global__ __launch_bounds__(256, 4) void k_energy(
    const float* __restrict__ feat, const float* __restrict__ rec,
    const float* __restrict__ ws, float* __restrict__ aws) {
  __shared__ float ben[4], brc[4];
  const int tid = threadIdx.x, lane = tid & 63, wv = tid >> 6;
  const int gw = blockIdx.x * 4 + wv;          // 0..4095
  const int ROWS = B_SIZE / (EN_BLK * 4);      // 64
  const int base = gw * ROWS;
  const int cl = lane & 15, g = lane >> 4;
  const int p0 = g * 8;

  const __fp16* l16 = (const __fp16*)(ws + WS_L16);
  v8h mf[17];
#pragma unroll
  for (int t = 0; t < 17; ++t)
    mf[t] = *(const v8h*)(l16 + (size_t)(16 * t + cl) * 32 + p0);
  float c1[8];
#pragma unroll
  for (int k = 0; k < 8; ++k) c1[k] = ws[WS_C1 + k];

  float en_acc = 0.f, rv_acc = 0.f;
  const v4f zf = {0.f, 0.f, 0.f, 0.f};

  for (int ch = 0; ch < ROWS / 16; ++ch) {
    const int b0 = base + ch * 16;
    const size_t row = (size_t)(b0 + cl) * 32;
    const float4 fa = *(const float4*)(feat + row + p0);
    const float4 fb = *(const float4*)(feat + row + p0 + 4);
    PkU af;
    af.p[0] = __builtin_amdgcn_cvt_pkrtz(fa.x, fa.y);
    af.p[1] = __builtin_amdgcn_cvt_pkrtz(fa.z, fa.w);
    af.p[2] = __builtin_amdgcn_cvt_pkrtz(fb.x, fb.y);
    af.p[3] = __builtin_amdgcn_cvt_pkrtz(fb.z, fb.w);

    float zk[8];
#pragma unroll
    for (int k = 0; k < 8; ++k) zk[k] = 0.f;
    float yq[4];

#pragma unroll
    for (int t = 0; t < 17; ++t) {
      const v4f y = __builtin_amdgcn_mfma_f32_16x16x32_f16(mf[t], af.v, zf, 0, 0, 0);
      if (t < 16) {
#pragma unroll
        for (int r = 0; r < 4; ++r) zk[t >> 1] = fmaf(y[r], y[r], zk[t >> 1]);
      } else {
#pragma unroll
        for (int r = 0; r < 4; ++r) yq[r] = y[r];
      }
    }
    // sum |y|^2 over the 4 g-groups (lanes differing in bits 4,5)
#pragma unroll
    for (int m = 16; m < 64; m <<= 1)
#pragma unroll
      for (int k = 0; k < 8; ++k) zk[k] += __shfl_xor(zk[k], m);

    float mx = -3.0e38f, s = 0.f;
#pragma unroll
    for (int k = 0; k < 8; ++k) {
      const float yp = __shfl(yq[k & 3], cl + ((k >> 2) << 4));  // f.q_k
      const float w = c1[k] + yp - 0.5f * zk[k];
      const float mn = fmaxf(mx, w);
      s = s * __expf(mx - mn) + __expf(w - mn);
      mx = mn;
    }
    float en = -(mx + __logf(s + 1e-10f));
    en = (en == en && en < 1e38f && en > -1e38f) ? en : 0.f;
    if (lane < 16) {                     // one of the 4 duplicate g-lanes
      en_acc += en;
      rv_acc += rec[b0 + cl];
    }
  }
#pragma unroll
  for (int m = 32; m; m >>= 1) {
    en_acc += __shfl_down(en_acc, m);
    rv_acc += __shfl_down(rv_acc, m);
  }
  if (lane == 0) { ben[wv] = en_acc; brc[wv] = rv_acc; }
  __syncthreads();
  if (tid == 0) {
    aws[WS_ENP + blockIdx.x] = ben[0] + ben[1] + ben[2] + ben[3];
    aws[WS_RCP + blockIdx.x] = brc[0] + brc[1] + brc[2] + brc[3];
  }
}

// ---------------------------------------------------------------------------
// Kernel 4: final reduction + combine.
// ---------------------------------------------------------------------------
__global__ void k_final(const float* __restrict__ ws, float* __restrict__ out) {
  __shared__ float r1[256], r2[256];
  const int tid = threadIdx.x;
  float e = 0.f, r = 0.f;
  for (int i = tid; i < EN_BLK; i += 256) {
    e += ws[WS_ENP + i];
    r += ws[WS_RCP + i];
  }
  r1[tid] = e; r2[tid] = r;
  __syncthreads();
  for (int s = 128; s > 0; s >>= 1) {
    if (tid < s) { r1[tid] += r1[tid + s]; r2[tid] += r2[tid + s]; }
    __syncthreads();
  }
  if (tid == 0) {
    const float recm = r2[0] * (1.f / (float)B_SIZE);
    const float enm  = r1[0] * (1.f / (float)B_SIZE);
    out[0] = recm + 0.1f * enm + 0.005f * ws[WS_SING];
  }
}

extern "C" void kernel_launch(void* const* d_in, const int* in_sizes, int n_in,
                              void* d_out, int out_size, void* d_ws, size_t ws_size,
                              hipStream_t stream) {
  const float* gamma = (const float*)d_in[0];
  const float* feat  = (const float*)d_in[1];
  const float* rec   = (const float*)d_in[2];
  float* ws = (float*)d_ws;
  float* out = (float*)d_out;

  hipLaunchKernelGGL(k_moments, dim3(MOM_BLK), dim3(512), 0, stream,
                     gamma, feat, ws + WS_PART);
  hipLaunchKernelGGL(k_reduce, dim3(34), dim3(256), 0, stream, ws + WS_PART, ws);
  hipLaunchKernelGGL(k_prepare, dim3(1), dim3(256), 0, stream, ws);
  hipLaunchKernelGGL(k_energy, dim3(EN_BLK), dim3(256), 0, stream, feat, rec, ws, ws);
  hipLaunchKernelGGL(k_final, dim3(1), dim3(256), 0, stream, ws, out);
}

// Round 6
// 159.463 us; speedup vs baseline: 2.8015x; 1.1779x over previous
//
#include <hip/hip_runtime.h>

using v8h  = __attribute__((ext_vector_type(8))) __fp16;
using h2   = __attribute__((ext_vector_type(2))) __fp16;
using v16f = __attribute__((ext_vector_type(16))) float;
using v4f  = __attribute__((ext_vector_type(4))) float;

#define B_SIZE 262144
// ws float offsets
#define WS_S2    0       // 8192 : S2[k][d][e]
#define WS_S1    8192    // 256  : S1[k][d]
#define WS_GS    8448    // 8    : gsum[k]
#define WS_SING  8456    // 8 : per-k singularity partials (summed in k_final)
#define WS_C1    8464    // 8 : log(phi)-0.5(logdet+Dlog2pi+|lmu|^2)
#define WS_L16   8736    // 4352 floats = 8704 halfs : M' [272 rows][32] f16
                         //   rows 0..255 Linv (k*32+j), 256..263 q_k, 264..271 zero
#define WS_ENP   13184   // 1024 energy partials
#define WS_RCP   14208   // 1024 recon partials
#define WS_PART  15360   // 256 x 8464 moment partials (8.7 MB)
#define PART_STRIDE 8464
#define MOM_BLK  256     // 512-thread blocks, 1024 rows each
#define EN_BLK   1024    // 256-thread blocks

union PkU { h2 p[4]; v8h v; };

// ---------------------------------------------------------------------------
// Kernel 1: raw moments. ONE k PER WAVE (8 waves/block), no spill, no atomics.
// ---------------------------------------------------------------------------
__global__ __launch_bounds__(512, 4) void k_moments(
    const float* __restrict__ gamma, const float* __restrict__ feat,
    float* __restrict__ part) {
  __shared__ float s2l[8 * 32 * 33];
  __shared__ float s1l[8 * 32];
  __shared__ float gsl[8];
  const int tid = threadIdx.x, lane = tid & 63, w = tid >> 6;  // w == k
  const int c = lane & 31, half = lane >> 5;
  const int ROWS = B_SIZE / MOM_BLK;           // 1024
  const int base = blockIdx.x * ROWS;

  v16f acc;
#pragma unroll
  for (int r = 0; r < 16; ++r) acc[r] = 0.f;
  float s1a = 0.f, ga = 0.f;

  for (int ch = 0; ch < ROWS / 16; ++ch) {     // 64 chunks of 16 rows
    const int rb = base + ch * 16 + half * 8;
    float fc[8], g8[8];
#pragma unroll
    for (int j = 0; j < 8; ++j) {
      fc[j] = feat[(size_t)(rb + j) * 32 + c];
      g8[j] = gamma[(size_t)(rb + j) * 8 + w];
    }
    PkU fp, gp;
#pragma unroll
    for (int jj = 0; jj < 4; ++jj) {
      fp.p[jj] = __builtin_amdgcn_cvt_pkrtz(fc[2 * jj], fc[2 * jj + 1]);
      gp.p[jj] = __builtin_amdgcn_cvt_pkrtz(g8[2 * jj], g8[2 * jj + 1]);
    }
#pragma unroll
    for (int j = 0; j < 8; ++j) {
      s1a = fmaf(g8[j], fc[j], s1a);
      ga += g8[j];
    }
    const v8h af = gp.v * fp.v;                // gamma_k ⊙ f
    acc = __builtin_amdgcn_mfma_f32_32x32x16_f16(af, fp.v, acc, 0, 0, 0);
  }

#pragma unroll
  for (int r = 0; r < 16; ++r) {
    const int row = (r & 3) + 8 * (r >> 2) + 4 * half;
    s2l[w * 1056 + row * 33 + c] = acc[r];
  }
  s1a += __shfl_xor(s1a, 32);
  ga  += __shfl_xor(ga, 32);
  if (half == 0) s1l[w * 32 + c] = s1a;
  if (lane == 0) gsl[w] = ga;
  __syncthreads();

  float* pb = part + (size_t)blockIdx.x * PART_STRIDE;
  for (int t = tid; t < 8192; t += 512) {
    const int k = t >> 10, row = (t >> 5) & 31, cc = t & 31;
    pb[t] = s2l[k * 1056 + row * 33 + cc];
  }
  if (tid < 256) pb[8192 + tid] = s1l[tid];
  if (tid < 8) pb[8448 + tid] = gsl[tid];
}

// ---------------------------------------------------------------------------
// Kernel 1b: deterministic partial reduction.
// ---------------------------------------------------------------------------
__global__ void k_reduce(const float* __restrict__ part, float* __restrict__ ws) {
  const int t = blockIdx.x * 256 + threadIdx.x;
  if (t >= 8456) return;
  float s = 0.f;
  for (int b = 0; b < MOM_BLK; ++b) s += part[(size_t)b * PART_STRIDE + t];
  ws[t] = s;
}

// ---------------------------------------------------------------------------
// Kernel 2: one k per BLOCK (8 blocks x 64 threads, single wave). All-register
// Cholesky + triangular solve; fully unrolled -> every cross-lane access is a
// compile-time readlane. No LDS in the hot chain, no barriers.
// ---------------------------------------------------------------------------
__global__ __launch_bounds__(64, 1) void k_prepare(float* __restrict__ ws) {
  const int k = blockIdx.x;
  const int i = threadIdx.x & 63;              // rows/cols 0..31; lanes 32+ ride along

  const float gs = ws[WS_GS + k];
  const float denom = gs + 1e-8f;
  const float s1i = (i < 32) ? ws[WS_S1 + k * 32 + i] : 0.f;
  const float mu_i = s1i / denom;

  // sigma row i into registers (8x float4)
  float a[32];
  {
    const int ri = i & 31;
    const float4* s2p = (const float4*)(ws + WS_S2 + k * 1024 + ri * 32);
    float4 q[8];
#pragma unroll
    for (int t = 0; t < 8; ++t) q[t] = s2p[t];
#pragma unroll
    for (int t = 0; t < 8; ++t) {
      a[4 * t + 0] = q[t].x; a[4 * t + 1] = q[t].y;
      a[4 * t + 2] = q[t].z; a[4 * t + 3] = q[t].w;
    }
  }
#pragma unroll
  for (int j = 0; j < 32; ++j) {
    const float muj = __shfl(mu_i, j);
    const float s1j = __shfl(s1i, j);
    float sig = a[j] - mu_i * s1j - muj * s1i + gs * mu_i * muj;
    sig = sig / denom + ((i == j) ? 1e-6f : 0.f);
    a[j] = sig;
  }
  // singularity partial for this k
  {
    float sing = 0.f;
#pragma unroll
    for (int j = 0; j < 32; ++j)
      if (i == j) sing = 1.f / (a[j] + 1e-8f);
    if (i >= 32) sing = 0.f;
#pragma unroll
    for (int m = 1; m < 32; m <<= 1) sing += __shfl_xor(sing, m);
    if (i == 0) ws[WS_SING + k] = sing;
  }

  // in-register right-looking Cholesky (lane i = row i)
  float logdet = 0.f;
#pragma unroll
  for (int j = 0; j < 32; ++j) {
    const float ajj = __shfl(a[j], j);
    const float ljj = sqrtf(ajj);
    float lij = (i == j) ? ljj : ((i > j && i < 32) ? a[j] / ljj : 0.f);
    a[j] = lij;
    if (i == j) logdet = logdet + 2.f * logf(ljj);
#pragma unroll
    for (int p = j + 1; p < 32; ++p) {
      const float lpj = __shfl(lij, p);
      a[p] = fmaf(-lij, lpj, a[p]);
    }
  }

  // forward substitution: lane c = column c of Linv;  L x = e_c
  const int c = i;
  float x[32];
#pragma unroll
  for (int r = 0; r < 32; ++r) {
    float s = (r == c) ? 1.f : 0.f;
#pragma unroll
    for (int p = 0; p < r; ++p) {
      const float lrp = __shfl(a[p], r);      // L[r][p], readlane
      s = fmaf(-lrp, x[p], s);
    }
    const float lrr = __shfl(a[r], r);
    x[r] = s / lrr;
  }

  // write Linv row-major f16: lane c writes column c
  __fp16* l16 = (__fp16*)(ws + WS_L16);
  if (c < 32) {
#pragma unroll
    for (int r = 0; r < 32; ++r)
      l16[(size_t)(k * 32 + r) * 32 + c] = (__fp16)x[r];
  }

  // lmu[j] = sum_c Linv[j][c] mu_c = reduce over lanes of x[j]*mu_c.
  // Compute per-lane contribution then butterfly-reduce each j via shfl.
  // Cheaper: lm_j = sum over lanes(x[j] * mu_i); do all 32 with xor-reduce on
  // a packed accumulator: process sequentially (32 x 5 shuffles is fine).
  float lm_mine = 0.f;                         // lane j ends with lm[j]
#pragma unroll
  for (int j = 0; j < 32; ++j) {
    float t = x[j] * mu_i;
    if (i >= 32) t = 0.f;
#pragma unroll
    for (int m = 1; m < 32; m <<= 1) t += __shfl_xor(t, m);
    if (i == j) lm_mine = t;                   // valid on lane j
  }
  // |lmu|^2
  float lm2 = lm_mine * lm_mine;
  if (i >= 32) lm2 = 0.f;
#pragma unroll
  for (int m = 1; m < 32; m <<= 1) lm2 += __shfl_xor(lm2, m);

  // q[c] = sum_j Linv[j][c] * lm[j] = sum_j x[j] * lm_j
  float q = 0.f;
#pragma unroll
  for (int j = 0; j < 32; ++j) {
    const float lmj = __shfl(lm_mine, j);
    q = fmaf(x[j], lmj, q);
  }
  if (c < 32) l16[(size_t)(256 + k) * 32 + c] = (__fp16)q;
  if (c < 32) l16[(size_t)(264 + k) * 32 + c] = (__fp16)0.f;  // zero pad rows

  if (i == 0) {
    const float phi = gs * (1.f / (float)B_SIZE);
    ws[WS_C1 + k] =
        logf(phi + 1e-10f) - 0.5f * (logdet + 32.f * logf(6.28318f)) - 0.5f * lm2;
  }
}

// ---------------------------------------------------------------------------
// Kernel 3: Y = M' F^T via 16x16x32 MFMA; w = c1' + f.q_k - 0.5|y|^2.
// ---------------------------------------------------------------------------
__global__ __launch_bounds__(256, 4) void k_energy(
    const float* __restrict__ feat, const float* __restrict__ rec,
    const float* __restrict__ ws, float* __restrict__ aws) {
  __shared__ float ben[4], brc[4];
  const int tid = threadIdx.x, lane = tid & 63, wv = tid >> 6;
  const int gw = blockIdx.x * 4 + wv;          // 0..4095
  const int ROWS = B_SIZE / (EN_BLK * 4);      // 64
  const int base = gw * ROWS;
  const int cl = lane & 15, g = lane >> 4;
  const int p0 = g * 8;

  const __fp16* l16 = (const __fp16*)(ws + WS_L16);
  v8h mf[17];
#pragma unroll
  for (int t = 0; t < 17; ++t)
    mf[t] = *(const v8h*)(l16 + (size_t)(16 * t + cl) * 32 + p0);
  float c1[8];
#pragma unroll
  for (int k = 0; k < 8; ++k) c1[k] = ws[WS_C1 + k];

  float en_acc = 0.f, rv_acc = 0.f;
  const v4f zf = {0.f, 0.f, 0.f, 0.f};

  for (int ch = 0; ch < ROWS / 16; ++ch) {
    const int b0 = base + ch * 16;
    const size_t row = (size_t)(b0 + cl) * 32;
    const float4 fa = *(const float4*)(feat + row + p0);
    const float4 fb = *(const float4*)(feat + row + p0 + 4);
    PkU af;
    af.p[0] = __builtin_amdgcn_cvt_pkrtz(fa.x, fa.y);
    af.p[1] = __builtin_amdgcn_cvt_pkrtz(fa.z, fa.w);
    af.p[2] = __builtin_amdgcn_cvt_pkrtz(fb.x, fb.y);
    af.p[3] = __builtin_amdgcn_cvt_pkrtz(fb.z, fb.w);

    float zk[8];
#pragma unroll
    for (int k = 0; k < 8; ++k) zk[k] = 0.f;
    float yq[4];

#pragma unroll
    for (int t = 0; t < 17; ++t) {
      const v4f y = __builtin_amdgcn_mfma_f32_16x16x32_f16(mf[t], af.v, zf, 0, 0, 0);
      if (t < 16) {
#pragma unroll
        for (int r = 0; r < 4; ++r) zk[t >> 1] = fmaf(y[r], y[r], zk[t >> 1]);
      } else {
#pragma unroll
        for (int r = 0; r < 4; ++r) yq[r] = y[r];
      }
    }
#pragma unroll
    for (int m = 16; m < 64; m <<= 1)
#pragma unroll
      for (int k = 0; k < 8; ++k) zk[k] += __shfl_xor(zk[k], m);

    float mx = -3.0e38f, s = 0.f;
#pragma unroll
    for (int k = 0; k < 8; ++k) {
      const float yp = __shfl(yq[k & 3], cl + ((k >> 2) << 4));  // f.q_k
      const float w = c1[k] + yp - 0.5f * zk[k];
      const float mn = fmaxf(mx, w);
      s = s * __expf(mx - mn) + __expf(w - mn);
      mx = mn;
    }
    float en = -(mx + __logf(s + 1e-10f));
    en = (en == en && en < 1e38f && en > -1e38f) ? en : 0.f;
    if (lane < 16) {
      en_acc += en;
      rv_acc += rec[b0 + cl];
    }
  }
#pragma unroll
  for (int m = 32; m; m >>= 1) {
    en_acc += __shfl_down(en_acc, m);
    rv_acc += __shfl_down(rv_acc, m);
  }
  if (lane == 0) { ben[wv] = en_acc; brc[wv] = rv_acc; }
  __syncthreads();
  if (tid == 0) {
    aws[WS_ENP + blockIdx.x] = ben[0] + ben[1] + ben[2] + ben[3];
    aws[WS_RCP + blockIdx.x] = brc[0] + brc[1] + brc[2] + brc[3];
  }
}

// ---------------------------------------------------------------------------
// Kernel 4: final reduction + combine (now also sums 8 per-k sing partials).
// ---------------------------------------------------------------------------
__global__ void k_final(const float* __restrict__ ws, float* __restrict__ out) {
  __shared__ float r1[256], r2[256];
  const int tid = threadIdx.x;
  float e = 0.f, r = 0.f;
  for (int i = tid; i < EN_BLK; i += 256) {
    e += ws[WS_ENP + i];
    r += ws[WS_RCP + i];
  }
  r1[tid] = e; r2[tid] = r;
  __syncthreads();
  for (int s = 128; s > 0; s >>= 1) {
    if (tid < s) { r1[tid] += r1[tid + s]; r2[tid] += r2[tid + s]; }
    __syncthreads();
  }
  if (tid == 0) {
    float sing = 0.f;
    for (int t = 0; t < 8; ++t) sing += ws[WS_SING + t];
    const float recm = r2[0] * (1.f / (float)B_SIZE);
    const float enm  = r1[0] * (1.f / (float)B_SIZE);
    out[0] = recm + 0.1f * enm + 0.005f * sing;
  }
}

extern "C" void kernel_launch(void* const* d_in, const int* in_sizes, int n_in,
                              void* d_out, int out_size, void* d_ws, size_t ws_size,
                              hipStream_t stream) {
  const float* gamma = (const float*)d_in[0];
  const float* feat  = (const float*)d_in[1];
  const float* rec   = (const float*)d_in[2];
  float* ws = (float*)d_ws;
  float* out = (float*)d_out;

  hipLaunchKernelGGL(k_moments, dim3(MOM_BLK), dim3(512), 0, stream,
                     gamma, feat, ws + WS_PART);
  hipLaunchKernelGGL(k_reduce, dim3(34), dim3(256), 0, stream, ws + WS_PART, ws);
  hipLaunchKernelGGL(k_prepare, dim3(8), dim3(64), 0, stream, ws);
  hipLaunchKernelGGL(k_energy, dim3(EN_BLK), dim3(256), 0, stream, feat, rec, ws, ws);
  hipLaunchKernelGGL(k_final, dim3(1), dim3(256), 0, stream, ws, out);
}

// Round 7
// 152.992 us; speedup vs baseline: 2.9200x; 1.0423x over previous
//
#include <hip/hip_runtime.h>

using v8h  = __attribute__((ext_vector_type(8))) __fp16;
using h2   = __attribute__((ext_vector_type(2))) __fp16;
using v16f = __attribute__((ext_vector_type(16))) float;
using v4f  = __attribute__((ext_vector_type(4))) float;

#define B_SIZE 262144
// ws float offsets
#define WS_S2    0       // 8192 : S2[k][d][e]
#define WS_S1    8192    // 256  : S1[k][d]
#define WS_GS    8448    // 8    : gsum[k]
#define WS_SING  8456    // 8 : per-k singularity partials (summed in k_final)
#define WS_C1    8464    // 8 : log(phi)-0.5(logdet+Dlog2pi+|lmu|^2)
#define WS_L16   8736    // 4352 floats = 8704 halfs : M' [272 rows][32] f16
                         //   rows 0..255 Linv (k*32+j), 256..263 q_k, 264..271 zero
#define WS_ENP   13184   // 1024 energy partials
#define WS_RCP   14208   // 1024 recon partials
#define WS_PART  15360   // 256 x 8464 moment partials (8.7 MB)
#define PART_STRIDE 8464
#define MOM_BLK  256     // 512-thread blocks, 1024 rows each
#define EN_BLK   1024    // 256-thread blocks

union PkU { h2 p[4]; v8h v; };

// SALU-path broadcast: v_readlane_b32 (~4 cyc) instead of ds_bpermute (~100 cyc)
__device__ __forceinline__ float lane_bcast(float v, int l) {
  return __builtin_bit_cast(float,
      __builtin_amdgcn_readlane(__builtin_bit_cast(int, v), l));
}

// ---------------------------------------------------------------------------
// Kernel 1: raw moments. ONE k PER WAVE (8 waves/block), no spill, no atomics.
// ---------------------------------------------------------------------------
__global__ __launch_bounds__(512, 4) void k_moments(
    const float* __restrict__ gamma, const float* __restrict__ feat,
    float* __restrict__ part) {
  __shared__ float s2l[8 * 32 * 33];
  __shared__ float s1l[8 * 32];
  __shared__ float gsl[8];
  const int tid = threadIdx.x, lane = tid & 63, w = tid >> 6;  // w == k
  const int c = lane & 31, half = lane >> 5;
  const int ROWS = B_SIZE / MOM_BLK;           // 1024
  const int base = blockIdx.x * ROWS;

  v16f acc;
#pragma unroll
  for (int r = 0; r < 16; ++r) acc[r] = 0.f;
  float s1a = 0.f, ga = 0.f;

  for (int ch = 0; ch < ROWS / 16; ++ch) {     // 64 chunks of 16 rows
    const int rb = base + ch * 16 + half * 8;
    float fc[8], g8[8];
#pragma unroll
    for (int j = 0; j < 8; ++j) {
      fc[j] = feat[(size_t)(rb + j) * 32 + c];
      g8[j] = gamma[(size_t)(rb + j) * 8 + w];
    }
    PkU fp, gp;
#pragma unroll
    for (int jj = 0; jj < 4; ++jj) {
      fp.p[jj] = __builtin_amdgcn_cvt_pkrtz(fc[2 * jj], fc[2 * jj + 1]);
      gp.p[jj] = __builtin_amdgcn_cvt_pkrtz(g8[2 * jj], g8[2 * jj + 1]);
    }
#pragma unroll
    for (int j = 0; j < 8; ++j) {
      s1a = fmaf(g8[j], fc[j], s1a);
      ga += g8[j];
    }
    const v8h af = gp.v * fp.v;                // gamma_k ⊙ f
    acc = __builtin_amdgcn_mfma_f32_32x32x16_f16(af, fp.v, acc, 0, 0, 0);
  }

#pragma unroll
  for (int r = 0; r < 16; ++r) {
    const int row = (r & 3) + 8 * (r >> 2) + 4 * half;
    s2l[w * 1056 + row * 33 + c] = acc[r];
  }
  s1a += __shfl_xor(s1a, 32);
  ga  += __shfl_xor(ga, 32);
  if (half == 0) s1l[w * 32 + c] = s1a;
  if (lane == 0) gsl[w] = ga;
  __syncthreads();

  float* pb = part + (size_t)blockIdx.x * PART_STRIDE;
  for (int t = tid; t < 8192; t += 512) {
    const int k = t >> 10, row = (t >> 5) & 31, cc = t & 31;
    pb[t] = s2l[k * 1056 + row * 33 + cc];
  }
  if (tid < 256) pb[8192 + tid] = s1l[tid];
  if (tid < 8) pb[8448 + tid] = gsl[tid];
}

// ---------------------------------------------------------------------------
// Kernel 1b: deterministic partial reduction.
// ---------------------------------------------------------------------------
__global__ void k_reduce(const float* __restrict__ part, float* __restrict__ ws) {
  const int t = blockIdx.x * 256 + threadIdx.x;
  if (t >= 8456) return;
  float s = 0.f;
  for (int b = 0; b < MOM_BLK; ++b) s += part[(size_t)b * PART_STRIDE + t];
  ws[t] = s;
}

// ---------------------------------------------------------------------------
// Kernel 2: one k per block, single wave. All-register Cholesky + solves with
// v_readlane broadcasts (SALU) + native rcp/sqrt/log. One LDS transpose for
// the Linv row view (conflict-free stride 33), one barrier total.
// Lanes 32..63 mirror lanes 0..31 (masked out of reductions/writes).
// ---------------------------------------------------------------------------
__global__ __launch_bounds__(64, 1) void k_prepare(float* __restrict__ ws) {
  __shared__ float T[32 * 33];
  const int k = blockIdx.x;
  const int i = threadIdx.x & 63;
  const int ri = i & 31;
  const bool act = i < 32;

  const float gs = ws[WS_GS + k];
  const float denom = gs + 1e-8f;
  const float rden = __builtin_amdgcn_rcpf(denom);
  const float s1i = ws[WS_S1 + k * 32 + ri];
  const float mu_i = s1i * rden;

  // sigma row ri into registers
  float a[32];
  {
    const float4* s2p = (const float4*)(ws + WS_S2 + k * 1024 + ri * 32);
    float4 q4[8];
#pragma unroll
    for (int t = 0; t < 8; ++t) q4[t] = s2p[t];
#pragma unroll
    for (int t = 0; t < 8; ++t) {
      a[4 * t + 0] = q4[t].x; a[4 * t + 1] = q4[t].y;
      a[4 * t + 2] = q4[t].z; a[4 * t + 3] = q4[t].w;
    }
  }
  float sing = 0.f;
#pragma unroll
  for (int j = 0; j < 32; ++j) {
    const float muj = lane_bcast(mu_i, j);
    const float s1j = lane_bcast(s1i, j);
    float sig = a[j] - mu_i * s1j - muj * s1i + gs * mu_i * muj;
    sig = sig * rden + ((ri == j) ? 1e-6f : 0.f);
    a[j] = sig;
    if (ri == j) sing = __builtin_amdgcn_rcpf(sig + 1e-8f);
  }
  if (!act) sing = 0.f;
#pragma unroll
  for (int m = 1; m < 64; m <<= 1) sing += __shfl_xor(sing, m);
  if (i == 0) ws[WS_SING + k] = sing;

  // in-register right-looking Cholesky (lane ri = row ri)
  float logdet = 0.f;
#pragma unroll
  for (int j = 0; j < 32; ++j) {
    const float ajj = lane_bcast(a[j], j);
    const float ljj = __builtin_amdgcn_sqrtf(ajj);
    const float rljj = __builtin_amdgcn_rcpf(ljj);
    logdet += __logf(ajj);                     // = 2*log(ljj)
    const float lij = (ri == j) ? ljj : ((ri > j) ? a[j] * rljj : 0.f);
    a[j] = lij;
#pragma unroll
    for (int p = j + 1; p < 32; ++p) {
      const float lpj = lane_bcast(lij, p);
      a[p] = fmaf(-lij, lpj, a[p]);
    }
  }

  // forward substitution: lane c = column c of Linv (L x = e_c)
  const int c = ri;
  float x[32];
#pragma unroll
  for (int r = 0; r < 32; ++r) {
    float s = (r == c) ? 1.f : 0.f;
#pragma unroll
    for (int p = 0; p < r; ++p) {
      const float lrp = lane_bcast(a[p], r);   // L[r][p] via readlane
      s = fmaf(-lrp, x[p], s);
    }
    x[r] = s * __builtin_amdgcn_rcpf(lane_bcast(a[r], r));
  }

  // LDS transpose: columns in -> rows out (stride 33, conflict-free)
  if (act) {
#pragma unroll
    for (int r = 0; r < 32; ++r) T[r * 33 + c] = x[r];
  }
  __syncthreads();
  float xr[32];                                // Linv row ri
#pragma unroll
  for (int p = 0; p < 32; ++p) xr[p] = T[ri * 33 + p];

  // f16 row store of Linv
  __fp16* l16 = (__fp16*)(ws + WS_L16);
  if (act) {
#pragma unroll
    for (int t = 0; t < 4; ++t) {
      PkU h4;
#pragma unroll
      for (int u = 0; u < 4; ++u)
        h4.p[u] = __builtin_amdgcn_cvt_pkrtz(xr[8 * t + 2 * u], xr[8 * t + 2 * u + 1]);
      *(v8h*)(l16 + (size_t)(k * 32 + ri) * 32 + 8 * t) = h4.v;
    }
  }

  // lmu_i = (Linv mu)[ri]  (readlane broadcasts of mu)
  float lm = 0.f;
#pragma unroll
  for (int p = 0; p < 32; ++p) lm = fmaf(xr[p], lane_bcast(mu_i, p), lm);

  // |lmu|^2
  float lm2 = act ? lm * lm : 0.f;
#pragma unroll
  for (int m = 1; m < 64; m <<= 1) lm2 += __shfl_xor(lm2, m);

  // q[c] = (Linv^T lmu)[c] = sum_j x[j] * lmu_j
  float q = 0.f;
#pragma unroll
  for (int j = 0; j < 32; ++j) q = fmaf(x[j], lane_bcast(lm, j), q);
  if (act) {
    l16[(size_t)(256 + k) * 32 + c] = (__fp16)q;
    l16[(size_t)(264 + k) * 32 + c] = (__fp16)0.f;   // zero pad rows
  }

  if (i == 0) {
    const float phi = gs * (1.f / (float)B_SIZE);
    ws[WS_C1 + k] =
        __logf(phi + 1e-10f) - 0.5f * (logdet + 32.f * logf(6.28318f)) - 0.5f * lm2;
  }
}

// ---------------------------------------------------------------------------
// Kernel 3: Y = M' F^T via 16x16x32 MFMA; w = c1' + f.q_k - 0.5|y|^2.
// ---------------------------------------------------------------------------
__global__ __launch_bounds__(256, 4) void k_energy(
    const float* __restrict__ feat, const float* __restrict__ rec,
    const float* __restrict__ ws, float* __restrict__ aws) {
  __shared__ float ben[4], brc[4];
  const int tid = threadIdx.x, lane = tid & 63, wv = tid >> 6;
  const int gw = blockIdx.x * 4 + wv;          // 0..4095
  const int ROWS = B_SIZE / (EN_BLK * 4);      // 64
  const int base = gw * ROWS;
  const int cl = lane & 15, g = lane >> 4;
  const int p0 = g * 8;

  const __fp16* l16 = (const __fp16*)(ws + WS_L16);
  v8h mf[17];
#pragma unroll
  for (int t = 0; t < 17; ++t)
    mf[t] = *(const v8h*)(l16 + (size_t)(16 * t + cl) * 32 + p0);
  float c1[8];
#pragma unroll
  for (int k = 0; k < 8; ++k) c1[k] = ws[WS_C1 + k];

  float en_acc = 0.f, rv_acc = 0.f;
  const v4f zf = {0.f, 0.f, 0.f, 0.f};

  for (int ch = 0; ch < ROWS / 16; ++ch) {
    const int b0 = base + ch * 16;
    const size_t row = (size_t)(b0 + cl) * 32;
    const float4 fa = *(const float4*)(feat + row + p0);
    const float4 fb = *(const float4*)(feat + row + p0 + 4);
    PkU af;
    af.p[0] = __builtin_amdgcn_cvt_pkrtz(fa.x, fa.y);
    af.p[1] = __builtin_amdgcn_cvt_pkrtz(fa.z, fa.w);
    af.p[2] = __builtin_amdgcn_cvt_pkrtz(fb.x, fb.y);
    af.p[3] = __builtin_amdgcn_cvt_pkrtz(fb.z, fb.w);

    float zk[8];
#pragma unroll
    for (int k = 0; k < 8; ++k) zk[k] = 0.f;
    float yq[4];

#pragma unroll
    for (int t = 0; t < 17; ++t) {
      const v4f y = __builtin_amdgcn_mfma_f32_16x16x32_f16(mf[t], af.v, zf, 0, 0, 0);
      if (t < 16) {
#pragma unroll
        for (int r = 0; r < 4; ++r) zk[t >> 1] = fmaf(y[r], y[r], zk[t >> 1]);
      } else {
#pragma unroll
        for (int r = 0; r < 4; ++r) yq[r] = y[r];
      }
    }
#pragma unroll
    for (int m = 16; m < 64; m <<= 1)
#pragma unroll
      for (int k = 0; k < 8; ++k) zk[k] += __shfl_xor(zk[k], m);

    float mx = -3.0e38f, s = 0.f;
#pragma unroll
    for (int k = 0; k < 8; ++k) {
      const float yp = __shfl(yq[k & 3], cl + ((k >> 2) << 4));  // f.q_k
      const float w = c1[k] + yp - 0.5f * zk[k];
      const float mn = fmaxf(mx, w);
      s = s * __expf(mx - mn) + __expf(w - mn);
      mx = mn;
    }
    float en = -(mx + __logf(s + 1e-10f));
    en = (en == en && en < 1e38f && en > -1e38f) ? en : 0.f;
    if (lane < 16) {
      en_acc += en;
      rv_acc += rec[b0 + cl];
    }
  }
#pragma unroll
  for (int m = 32; m; m >>= 1) {
    en_acc += __shfl_down(en_acc, m);
    rv_acc += __shfl_down(rv_acc, m);
  }
  if (lane == 0) { ben[wv] = en_acc; brc[wv] = rv_acc; }
  __syncthreads();
  if (tid == 0) {
    aws[WS_ENP + blockIdx.x] = ben[0] + ben[1] + ben[2] + ben[3];
    aws[WS_RCP + blockIdx.x] = brc[0] + brc[1] + brc[2] + brc[3];
  }
}

// ---------------------------------------------------------------------------
// Kernel 4: final reduction + combine.
// ---------------------------------------------------------------------------
__global__ void k_final(const float* __restrict__ ws, float* __restrict__ out) {
  __shared__ float r1[256], r2[256];
  const int tid = threadIdx.x;
  float e = 0.f, r = 0.f;
  for (int i = tid; i < EN_BLK; i += 256) {
    e += ws[WS_ENP + i];
    r += ws[WS_RCP + i];
  }
  r1[tid] = e; r2[tid] = r;
  __syncthreads();
  for (int s = 128; s > 0; s >>= 1) {
    if (tid < s) { r1[tid] += r1[tid + s]; r2[tid] += r2[tid + s]; }
    __syncthreads();
  }
  if (tid == 0) {
    float sing = 0.f;
    for (int t = 0; t < 8; ++t) sing += ws[WS_SING + t];
    const float recm = r2[0] * (1.f / (float)B_SIZE);
    const float enm  = r1[0] * (1.f / (float)B_SIZE);
    out[0] = recm + 0.1f * enm + 0.005f * sing;
  }
}

extern "C" void kernel_launch(void* const* d_in, const int* in_sizes, int n_in,
                              void* d_out, int out_size, void* d_ws, size_t ws_size,
                              hipStream_t stream) {
  const float* gamma = (const float*)d_in[0];
  const float* feat  = (const float*)d_in[1];
  const float* rec   = (const float*)d_in[2];
  float* ws = (float*)d_ws;
  float* out = (float*)d_out;

  hipLaunchKernelGGL(k_moments, dim3(MOM_BLK), dim3(512), 0, stream,
                     gamma, feat, ws + WS_PART);
  hipLaunchKernelGGL(k_reduce, dim3(34), dim3(256), 0, stream, ws + WS_PART, ws);
  hipLaunchKernelGGL(k_prepare, dim3(8), dim3(64), 0, stream, ws);
  hipLaunchKernelGGL(k_energy, dim3(EN_BLK), dim3(256), 0, stream, feat, rec, ws, ws);
  hipLaunchKernelGGL(k_final, dim3(1), dim3(256), 0, stream, ws, out);
}

// Round 8
// 132.391 us; speedup vs baseline: 3.3743x; 1.1556x over previous
//
#include <hip/hip_runtime.h>

using v8h  = __attribute__((ext_vector_type(8))) __fp16;
using h2   = __attribute__((ext_vector_type(2))) __fp16;
using v16f = __attribute__((ext_vector_type(16))) float;
using v4f  = __attribute__((ext_vector_type(4))) float;

#define B_SIZE 262144
// ws float offsets
#define WS_S2    0       // 8192 : S2[k][d][e]
#define WS_S1    8192    // 256  : S1[k][d]
#define WS_GS    8448    // 8    : gsum[k]
#define WS_SING  8456    // 8 : per-k singularity partials (summed in k_final)
#define WS_C1    8464    // 8 : log(phi)-0.5(logdet+Dlog2pi+|lmu|^2)
#define WS_L16   8736    // 4352 floats = 8704 halfs : M' [272 rows][32] f16
#define WS_ENP   13184   // 1024 energy partials
#define WS_RCP   14208   // 1024 recon partials
#define WS_PART  15360   // 256 x 8464 moment partials (8.7 MB)
#define WS_PART2 2182144 // 8 x 8464 stage-1 reduce partials
#define PART_STRIDE 8464
#define MOM_BLK  256     // 1024-thread blocks, 1024 rows each
#define EN_BLK   1024    // 256-thread blocks

union PkU { h2 p[4]; v8h v; };

__device__ __forceinline__ float lane_bcast(float v, int l) {
  return __builtin_bit_cast(float,
      __builtin_amdgcn_readlane(__builtin_bit_cast(int, v), l));
}

// ---------------------------------------------------------------------------
// Kernel 1: raw moments. 16 waves/block: wave w -> k = w&7, row-half = w>>3.
// 16 exclusive LDS tiles folded pairwise in the epilogue. No atomics.
// ---------------------------------------------------------------------------
__global__ __launch_bounds__(1024, 4) void k_moments(
    const float* __restrict__ gamma, const float* __restrict__ feat,
    float* __restrict__ part) {
  __shared__ float s2l[16 * 1056];
  __shared__ float s1l[16 * 32];
  __shared__ float gsl[16];
  const int tid = threadIdx.x, lane = tid & 63, w = tid >> 6;   // w 0..15
  const int k = w & 7, hsel = w >> 3;
  const int c = lane & 31, half = lane >> 5;
  const int base = blockIdx.x * 1024 + hsel * 512;

  v16f acc;
#pragma unroll
  for (int r = 0; r < 16; ++r) acc[r] = 0.f;
  float s1a = 0.f, ga = 0.f;

#pragma unroll 2
  for (int ch = 0; ch < 32; ++ch) {            // 32 chunks of 16 rows
    const int rb = base + ch * 16 + half * 8;
    float fc[8], g8[8];
#pragma unroll
    for (int j = 0; j < 8; ++j) {
      fc[j] = feat[(size_t)(rb + j) * 32 + c];
      g8[j] = gamma[(size_t)(rb + j) * 8 + k];
    }
    PkU fp, gp;
#pragma unroll
    for (int jj = 0; jj < 4; ++jj) {
      fp.p[jj] = __builtin_amdgcn_cvt_pkrtz(fc[2 * jj], fc[2 * jj + 1]);
      gp.p[jj] = __builtin_amdgcn_cvt_pkrtz(g8[2 * jj], g8[2 * jj + 1]);
    }
#pragma unroll
    for (int j = 0; j < 8; ++j) {
      s1a = fmaf(g8[j], fc[j], s1a);
      ga += g8[j];
    }
    const v8h af = gp.v * fp.v;                // gamma_k ⊙ f
    acc = __builtin_amdgcn_mfma_f32_32x32x16_f16(af, fp.v, acc, 0, 0, 0);
  }

#pragma unroll
  for (int r = 0; r < 16; ++r) {
    const int row = (r & 3) + 8 * (r >> 2) + 4 * half;
    s2l[w * 1056 + row * 33 + c] = acc[r];
  }
  s1a += __shfl_xor(s1a, 32);
  ga  += __shfl_xor(ga, 32);
  if (half == 0) s1l[w * 32 + c] = s1a;
  if (lane == 0) gsl[w] = ga;
  __syncthreads();

  float* pb = part + (size_t)blockIdx.x * PART_STRIDE;
  for (int t = tid; t < 8192; t += 1024) {
    const int kk = t >> 10, row = (t >> 5) & 31, cc = t & 31;
    pb[t] = s2l[kk * 1056 + row * 33 + cc] + s2l[(kk + 8) * 1056 + row * 33 + cc];
  }
  if (tid < 256) pb[8192 + tid] = s1l[tid] + s1l[tid + 256];
  if (tid < 8) pb[8448 + tid] = gsl[tid] + gsl[tid + 8];
}

// ---------------------------------------------------------------------------
// Kernel 1b stage 1: block (x,y) sums partials b in [y*32, y*32+32).
// ---------------------------------------------------------------------------
__global__ void k_reduce(const float* __restrict__ part, float* __restrict__ p2) {
  const int t = blockIdx.x * 256 + threadIdx.x;
  if (t >= 8456) return;
  const int y = blockIdx.y;
  float s = 0.f;
#pragma unroll 8
  for (int b = y * 32; b < y * 32 + 32; ++b)
    s += part[(size_t)b * PART_STRIDE + t];
  p2[(size_t)y * PART_STRIDE + t] = s;
}

// stage 2: sum the 8 stage-1 slices.
__global__ void k_reduce2(const float* __restrict__ p2, float* __restrict__ ws) {
  const int t = blockIdx.x * 256 + threadIdx.x;
  if (t >= 8456) return;
  float s = 0.f;
#pragma unroll
  for (int y = 0; y < 8; ++y) s += p2[(size_t)y * PART_STRIDE + t];
  ws[t] = s;
}

// ---------------------------------------------------------------------------
// Kernel 2: one k per block, single wave; readlane broadcasts + native
// rcp/sqrt/log; one LDS transpose, one barrier.
// ---------------------------------------------------------------------------
__global__ __launch_bounds__(64, 1) void k_prepare(float* __restrict__ ws) {
  __shared__ float T[32 * 33];
  const int k = blockIdx.x;
  const int i = threadIdx.x & 63;
  const int ri = i & 31;
  const bool act = i < 32;

  const float gs = ws[WS_GS + k];
  const float denom = gs + 1e-8f;
  const float rden = __builtin_amdgcn_rcpf(denom);
  const float s1i = ws[WS_S1 + k * 32 + ri];
  const float mu_i = s1i * rden;

  float a[32];
  {
    const float4* s2p = (const float4*)(ws + WS_S2 + k * 1024 + ri * 32);
    float4 q4[8];
#pragma unroll
    for (int t = 0; t < 8; ++t) q4[t] = s2p[t];
#pragma unroll
    for (int t = 0; t < 8; ++t) {
      a[4 * t + 0] = q4[t].x; a[4 * t + 1] = q4[t].y;
      a[4 * t + 2] = q4[t].z; a[4 * t + 3] = q4[t].w;
    }
  }
  float sing = 0.f;
#pragma unroll
  for (int j = 0; j < 32; ++j) {
    const float muj = lane_bcast(mu_i, j);
    const float s1j = lane_bcast(s1i, j);
    float sig = a[j] - mu_i * s1j - muj * s1i + gs * mu_i * muj;
    sig = sig * rden + ((ri == j) ? 1e-6f : 0.f);
    a[j] = sig;
    if (ri == j) sing = __builtin_amdgcn_rcpf(sig + 1e-8f);
  }
  if (!act) sing = 0.f;
#pragma unroll
  for (int m = 1; m < 64; m <<= 1) sing += __shfl_xor(sing, m);
  if (i == 0) ws[WS_SING + k] = sing;

  float logdet = 0.f;
#pragma unroll
  for (int j = 0; j < 32; ++j) {
    const float ajj = lane_bcast(a[j], j);
    const float ljj = __builtin_amdgcn_sqrtf(ajj);
    const float rljj = __builtin_amdgcn_rcpf(ljj);
    logdet += __logf(ajj);
    const float lij = (ri == j) ? ljj : ((ri > j) ? a[j] * rljj : 0.f);
    a[j] = lij;
#pragma unroll
    for (int p = j + 1; p < 32; ++p) {
      const float lpj = lane_bcast(lij, p);
      a[p] = fmaf(-lij, lpj, a[p]);
    }
  }

  const int c = ri;
  float x[32];
#pragma unroll
  for (int r = 0; r < 32; ++r) {
    float s = (r == c) ? 1.f : 0.f;
#pragma unroll
    for (int p = 0; p < r; ++p) {
      const float lrp = lane_bcast(a[p], r);
      s = fmaf(-lrp, x[p], s);
    }
    x[r] = s * __builtin_amdgcn_rcpf(lane_bcast(a[r], r));
  }

  if (act) {
#pragma unroll
    for (int r = 0; r < 32; ++r) T[r * 33 + c] = x[r];
  }
  __syncthreads();
  float xr[32];
#pragma unroll
  for (int p = 0; p < 32; ++p) xr[p] = T[ri * 33 + p];

  __fp16* l16 = (__fp16*)(ws + WS_L16);
  if (act) {
#pragma unroll
    for (int t = 0; t < 4; ++t) {
      PkU h4;
#pragma unroll
      for (int u = 0; u < 4; ++u)
        h4.p[u] = __builtin_amdgcn_cvt_pkrtz(xr[8 * t + 2 * u], xr[8 * t + 2 * u + 1]);
      *(v8h*)(l16 + (size_t)(k * 32 + ri) * 32 + 8 * t) = h4.v;
    }
  }

  float lm = 0.f;
#pragma unroll
  for (int p = 0; p < 32; ++p) lm = fmaf(xr[p], lane_bcast(mu_i, p), lm);

  float lm2 = act ? lm * lm : 0.f;
#pragma unroll
  for (int m = 1; m < 64; m <<= 1) lm2 += __shfl_xor(lm2, m);

  float q = 0.f;
#pragma unroll
  for (int j = 0; j < 32; ++j) q = fmaf(x[j], lane_bcast(lm, j), q);
  if (act) {
    l16[(size_t)(256 + k) * 32 + c] = (__fp16)q;
    l16[(size_t)(264 + k) * 32 + c] = (__fp16)0.f;
  }

  if (i == 0) {
    const float phi = gs * (1.f / (float)B_SIZE);
    ws[WS_C1 + k] =
        __logf(phi + 1e-10f) - 0.5f * (logdet + 32.f * logf(6.28318f)) - 0.5f * lm2;
  }
}

// ---------------------------------------------------------------------------
// Kernel 3: Y = M' F^T via 16x16x32 MFMA; w = c1' + f.q_k - 0.5|y|^2.
// ---------------------------------------------------------------------------
__global__ __launch_bounds__(256, 4) void k_energy(
    const float* __restrict__ feat, const float* __restrict__ rec,
    const float* __restrict__ ws, float* __restrict__ aws) {
  __shared__ float ben[4], brc[4];
  const int tid = threadIdx.x, lane = tid & 63, wv = tid >> 6;
  const int gw = blockIdx.x * 4 + wv;
  const int ROWS = B_SIZE / (EN_BLK * 4);      // 64
  const int base = gw * ROWS;
  const int cl = lane & 15, g = lane >> 4;
  const int p0 = g * 8;

  const __fp16* l16 = (const __fp16*)(ws + WS_L16);
  v8h mf[17];
#pragma unroll
  for (int t = 0; t < 17; ++t)
    mf[t] = *(const v8h*)(l16 + (size_t)(16 * t + cl) * 32 + p0);
  float c1[8];
#pragma unroll
  for (int k = 0; k < 8; ++k) c1[k] = ws[WS_C1 + k];

  float en_acc = 0.f, rv_acc = 0.f;
  const v4f zf = {0.f, 0.f, 0.f, 0.f};

  for (int ch = 0; ch < ROWS / 16; ++ch) {
    const int b0 = base + ch * 16;
    const size_t row = (size_t)(b0 + cl) * 32;
    const float4 fa = *(const float4*)(feat + row + p0);
    const float4 fb = *(const float4*)(feat + row + p0 + 4);
    PkU af;
    af.p[0] = __builtin_amdgcn_cvt_pkrtz(fa.x, fa.y);
    af.p[1] = __builtin_amdgcn_cvt_pkrtz(fa.z, fa.w);
    af.p[2] = __builtin_amdgcn_cvt_pkrtz(fb.x, fb.y);
    af.p[3] = __builtin_amdgcn_cvt_pkrtz(fb.z, fb.w);

    float zk[8];
#pragma unroll
    for (int k = 0; k < 8; ++k) zk[k] = 0.f;
    float yq[4];

#pragma unroll
    for (int t = 0; t < 17; ++t) {
      const v4f y = __builtin_amdgcn_mfma_f32_16x16x32_f16(mf[t], af.v, zf, 0, 0, 0);
      if (t < 16) {
#pragma unroll
        for (int r = 0; r < 4; ++r) zk[t >> 1] = fmaf(y[r], y[r], zk[t >> 1]);
      } else {
#pragma unroll
        for (int r = 0; r < 4; ++r) yq[r] = y[r];
      }
    }
#pragma unroll
    for (int m = 16; m < 64; m <<= 1)
#pragma unroll
      for (int k = 0; k < 8; ++k) zk[k] += __shfl_xor(zk[k], m);

    float mx = -3.0e38f, s = 0.f;
#pragma unroll
    for (int k = 0; k < 8; ++k) {
      const float yp = __shfl(yq[k & 3], cl + ((k >> 2) << 4));
      const float w = c1[k] + yp - 0.5f * zk[k];
      const float mn = fmaxf(mx, w);
      s = s * __expf(mx - mn) + __expf(w - mn);
      mx = mn;
    }
    float en = -(mx + __logf(s + 1e-10f));
    en = (en == en && en < 1e38f && en > -1e38f) ? en : 0.f;
    if (lane < 16) {
      en_acc += en;
      rv_acc += rec[b0 + cl];
    }
  }
#pragma unroll
  for (int m = 32; m; m >>= 1) {
    en_acc += __shfl_down(en_acc, m);
    rv_acc += __shfl_down(rv_acc, m);
  }
  if (lane == 0) { ben[wv] = en_acc; brc[wv] = rv_acc; }
  __syncthreads();
  if (tid == 0) {
    aws[WS_ENP + blockIdx.x] = ben[0] + ben[1] + ben[2] + ben[3];
    aws[WS_RCP + blockIdx.x] = brc[0] + brc[1] + brc[2] + brc[3];
  }
}

// ---------------------------------------------------------------------------
// Kernel 4: final reduction + combine.
// ---------------------------------------------------------------------------
__global__ void k_final(const float* __restrict__ ws, float* __restrict__ out) {
  __shared__ float r1[256], r2[256];
  const int tid = threadIdx.x;
  float e = 0.f, r = 0.f;
  for (int i = tid; i < EN_BLK; i += 256) {
    e += ws[WS_ENP + i];
    r += ws[WS_RCP + i];
  }
  r1[tid] = e; r2[tid] = r;
  __syncthreads();
  for (int s = 128; s > 0; s >>= 1) {
    if (tid < s) { r1[tid] += r1[tid + s]; r2[tid] += r2[tid + s]; }
    __syncthreads();
  }
  if (tid == 0) {
    float sing = 0.f;
    for (int t = 0; t < 8; ++t) sing += ws[WS_SING + t];
    const float recm = r2[0] * (1.f / (float)B_SIZE);
    const float enm  = r1[0] * (1.f / (float)B_SIZE);
    out[0] = recm + 0.1f * enm + 0.005f * sing;
  }
}

extern "C" void kernel_launch(void* const* d_in, const int* in_sizes, int n_in,
                              void* d_out, int out_size, void* d_ws, size_t ws_size,
                              hipStream_t stream) {
  const float* gamma = (const float*)d_in[0];
  const float* feat  = (const float*)d_in[1];
  const float* rec   = (const float*)d_in[2];
  float* ws = (float*)d_ws;
  float* out = (float*)d_out;

  hipLaunchKernelGGL(k_moments, dim3(MOM_BLK), dim3(1024), 0, stream,
                     gamma, feat, ws + WS_PART);
  hipLaunchKernelGGL(k_reduce, dim3(34, 8), dim3(256), 0, stream,
                     ws + WS_PART, ws + WS_PART2);
  hipLaunchKernelGGL(k_reduce2, dim3(34), dim3(256), 0, stream, ws + WS_PART2, ws);
  hipLaunchKernelGGL(k_prepare, dim3(8), dim3(64), 0, stream, ws);
  hipLaunchKernelGGL(k_energy, dim3(EN_BLK), dim3(256), 0, stream, feat, rec, ws, ws);
  hipLaunchKernelGGL(k_final, dim3(1), dim3(256), 0, stream, ws, out);
}